// Round 1
// 1430.018 us; speedup vs baseline: 1.0547x; 1.0547x over previous
//
#include <hip/hip_runtime.h>
#include <cstdint>
#include <cstddef>

// Problem constants
#define BB 16
#define NN 1024
#define HD 256
#define IND 128
#define OUTD 1024
#define MROWS (BB*NN)          // 16384

#define LEAKY(x) ((x) >= 0.0f ? (x) : 0.01f*(x))

typedef short short8 __attribute__((ext_vector_type(8)));
typedef float f32x4 __attribute__((ext_vector_type(4)));

// 16B async global->LDS DMA. LDS dest is wave-uniform base + lane*16 (linear);
// swizzling is done on the GLOBAL source address + on the ds_read side (same
// XOR involution both sides).
#define GLL16(gsrc, ldst) __builtin_amdgcn_global_load_lds( \
    (const __attribute__((address_space(1))) unsigned int*)(gsrc), \
    (__attribute__((address_space(3))) unsigned int*)(ldst), 16, 0, 0)

// ---------------- wave helpers ----------------
__device__ inline float wave_sum(float v){
  #pragma unroll
  for (int off=32; off; off>>=1) v += __shfl_xor(v, off, 64);
  return v;
}
__device__ inline float wave_max(float v){
  #pragma unroll
  for (int off=32; off; off>>=1) v = fmaxf(v, __shfl_xor(v, off, 64));
  return v;
}

// fp32 -> bf16 round-to-nearest-even; bf16 -> fp32
__device__ inline unsigned short f2bf(float x){
  unsigned u = __float_as_uint(x);
  unsigned r = (u + 0x7fffu + ((u >> 16) & 1u)) >> 16;
  return (unsigned short)r;
}
__device__ inline float bf2f(unsigned short h){
  return __uint_as_float((unsigned)h << 16);
}

// ---------------- JAX threefry2x32 gumbel noise (partitionable) ----------------
// NOTE: logf kept as libm (precise) — v_log near 1 is inaccurate and the outer
// log amplifies it; this path must stay bit-stable vs the passing version.
__device__ inline float gumbel_noise(unsigned m){
  const unsigned k0 = 0u, k1 = 42u;
  const unsigned ks2 = k0 ^ k1 ^ 0x1BD11BDAu;
  unsigned x0 = 0u, x1 = m;
  x0 += k0; x1 += k1;
  #define TF_ROUND(r) { x0 += x1; x1 = (x1 << (r)) | (x1 >> (32-(r))); x1 ^= x0; }
  TF_ROUND(13) TF_ROUND(15) TF_ROUND(26) TF_ROUND(6)
  x0 += k1;  x1 += ks2 + 1u;
  TF_ROUND(17) TF_ROUND(29) TF_ROUND(16) TF_ROUND(24)
  x0 += ks2; x1 += k0 + 2u;
  TF_ROUND(13) TF_ROUND(15) TF_ROUND(26) TF_ROUND(6)
  x0 += k0;  x1 += k1 + 3u;
  TF_ROUND(17) TF_ROUND(29) TF_ROUND(16) TF_ROUND(24)
  x0 += k1;  x1 += ks2 + 4u;
  TF_ROUND(13) TF_ROUND(15) TF_ROUND(26) TF_ROUND(6)
  x0 += ks2; x1 += k0 + 5u;
  #undef TF_ROUND
  unsigned bits = x0 ^ x1;
  float u = __uint_as_float((bits >> 9) | 0x3f800000u) - 1.0f;   // [0,1)
  float t = -logf(u + 1e-20f);
  return -logf(t + 1e-20f) * 0.05f;   // NOISE_SCALE
}

// ---------------- fused adj row stats + bf16 convert ----------------
__global__ __launch_bounds__(256) void adj_prep_k(const float* __restrict__ adj,
                                                  float* __restrict__ dis,
                                                  float* __restrict__ rinv,
                                                  unsigned short* __restrict__ abf){
  int tid = threadIdx.x, wid = tid >> 6, lane = tid & 63;
  int row = blockIdx.x*4 + wid;
  const float4* rp = (const float4*)(adj + (size_t)row*NN);
  ushort4* op = (ushort4*)(abf + (size_t)row*NN);
  float s = 0.f;
  #pragma unroll
  for (int p=0;p<4;p++){
    float4 v = rp[lane + p*64];
    s += v.x+v.y+v.z+v.w;
    ushort4 o;
    o.x = f2bf(v.x); o.y = f2bf(v.y); o.z = f2bf(v.z); o.w = f2bf(v.w);
    op[lane + p*64] = o;
  }
  s = wave_sum(s);
  if (lane==0){
    dis[row]  = 1.0f/sqrtf(s + 1.0f);
    rinv[row] = 1.0f/s;
  }
}

// ---------------- flat hi/lo split (weights, X) ----------------
__global__ __launch_bounds__(256) void split_flat_k(const float* __restrict__ src,
                                                    unsigned short* __restrict__ h,
                                                    unsigned short* __restrict__ l,
                                                    int n4){
  int gid = blockIdx.x*256 + threadIdx.x;
  if (gid >= n4) return;
  float4 v = ((const float4*)src)[gid];
  ushort4 hh, ll;
  hh.x = f2bf(v.x); ll.x = f2bf(v.x - bf2f(hh.x));
  hh.y = f2bf(v.y); ll.y = f2bf(v.y - bf2f(hh.y));
  hh.z = f2bf(v.z); ll.z = f2bf(v.z - bf2f(hh.z));
  hh.w = f2bf(v.w); ll.w = f2bf(v.w - bf2f(hh.w));
  ((ushort4*)h)[gid] = hh;
  ((ushort4*)l)[gid] = ll;
}

// fp32 [16][1024 i][ld] (cols 0..255) -> bf16 transposed [16][256 c][1024 i]
__global__ __launch_bounds__(256) void bconv_t_k(const float* __restrict__ in, int ld,
                                                 const float* __restrict__ scale,
                                                 unsigned short* __restrict__ outT){
  __shared__ float tile[64][68];
  int b  = blockIdx.z;
  int i0 = blockIdx.x*64;
  int c0 = blockIdx.y*64;
  const float* inb = in + (size_t)b*NN*ld;
  unsigned short* ob = outT + (size_t)b*HD*NN;
  int tid = threadIdx.x;
  #pragma unroll
  for (int it=0; it<4; it++){
    int f = tid + it*256;
    int r = f >> 4, c4 = (f & 15)*4;
    float4 v = *(const float4*)(inb + (size_t)(i0+r)*ld + c0 + c4);
    float s = scale ? scale[b*NN + i0 + r] : 1.0f;
    tile[r][c4+0]=v.x*s; tile[r][c4+1]=v.y*s; tile[r][c4+2]=v.z*s; tile[r][c4+3]=v.w*s;
  }
  __syncthreads();
  #pragma unroll
  for (int it=0; it<4; it++){
    int f = tid + it*256;
    int cl = f >> 4, r4 = (f & 15)*4;
    ushort4 o;
    o.x = f2bf(tile[r4+0][cl]);
    o.y = f2bf(tile[r4+1][cl]);
    o.z = f2bf(tile[r4+2][cl]);
    o.w = f2bf(tile[r4+3][cl]);
    *(ushort4*)(ob + (size_t)(c0+cl)*NN + i0 + r4) = o;
  }
}

// ---------------- elementwise ----------------
__global__ __launch_bounds__(256) void sub_abs_k(const float* __restrict__ a, int lda,
                                                 const float* __restrict__ bp, int ldb,
                                                 float* __restrict__ out){
  int gid = blockIdx.x*256 + threadIdx.x;
  int row = gid >> 6, c = (gid & 63)*4;
  float4 va = *(const float4*)(a  + (size_t)row*lda + c);
  float4 vb = *(const float4*)(bp + (size_t)row*ldb + c);
  float4 o = make_float4(fabsf(va.x-vb.x), fabsf(va.y-vb.y), fabsf(va.z-vb.z), fabsf(va.w-vb.w));
  *(float4*)(out + (size_t)row*HD + c) = o;
}

// ---------------- MFMA batched GEMM: acc = adj[b] @ B[b] ----------------
// DMA staging: global_load_lds 16B, linear [128][32] LDS, XOR slot-swizzle on
// source + read (slot ^= (row>>1)&3) -> 2-way (free) ds_read_b128 conflicts.
// mode 1: out = 0.5*(Bsrc[i][n] + sc_i*acc)
// mode 2: out = leaky(sc_i*(acc + sc_i*Bsrc[i][n]))
__global__ __launch_bounds__(512) void gemm_nn_mfma_k(const unsigned short* __restrict__ Abf,
                                                      const unsigned short* __restrict__ Btb,
                                                      const float* __restrict__ Bsrc, int ldb,
                                                      const float* __restrict__ rowscale,
                                                      float* __restrict__ out, int mode){
  __shared__ unsigned short Als[128][32];
  __shared__ unsigned short Bls[128][32];
  int b  = blockIdx.z;
  int n0 = blockIdx.x*128;
  int i0 = blockIdx.y*128;
  const unsigned short* Ab = Abf + (size_t)b*NN*NN + (size_t)i0*NN;
  const unsigned short* Bb = Btb + (size_t)b*HD*NN + (size_t)n0*NN;
  int tid = threadIdx.x;
  int wave = tid >> 6, lane = tid & 63;
  int quad = lane >> 4, l16 = lane & 15;
  int wr = (wave >> 2)*64;
  int wc = (wave & 3)*32;

  // staging geometry: thread -> (row r, 16B slot j); source col pre-swizzled
  int r  = tid >> 2;
  int cg = (((tid & 3) ^ ((r >> 1) & 3)) << 3);         // ushort col in 32
  int wbase = (tid >> 6) << 9;                          // wave's 1KB LDS chunk
  unsigned short* lA = &Als[0][0] + wbase;
  unsigned short* lB = &Bls[0][0] + wbase;
  const unsigned short* gA = Ab + (size_t)r*NN + cg;
  const unsigned short* gB = Bb + (size_t)r*NN + cg;

  f32x4 acc[4][2] = {};

  for (int kc = 0; kc < NN; kc += 32){
    GLL16(gA + kc, lA);
    GLL16(gB + kc, lB);
    __syncthreads();
    short8 af[4];
    #pragma unroll
    for (int rt=0; rt<4; rt++){
      int R = wr + rt*16 + l16;
      af[rt] = *(const short8*)&Als[R][(quad ^ ((R >> 1) & 3)) << 3];
    }
    #pragma unroll
    for (int ct=0; ct<2; ct++){
      int Rb = wc + ct*16 + l16;
      short8 bfr = *(const short8*)&Bls[Rb][(quad ^ ((Rb >> 1) & 3)) << 3];
      #pragma unroll
      for (int rt=0; rt<4; rt++)
        acc[rt][ct] = __builtin_amdgcn_mfma_f32_16x16x32_bf16(af[rt], bfr, acc[rt][ct], 0, 0, 0);
    }
    __syncthreads();
  }

  #pragma unroll
  for (int rt=0; rt<4; rt++){
    #pragma unroll
    for (int p=0; p<4; p++){
      int gr = i0 + wr + rt*16 + quad*4 + p;
      int gm = b*NN + gr;
      float sc = rowscale[gm];
      #pragma unroll
      for (int ct=0; ct<2; ct++){
        int gc = n0 + wc + ct*16 + l16;
        float a = acc[rt][ct][p];
        float src = Bsrc[(size_t)gm*ldb + gc];
        float o = (mode == 1) ? 0.5f*(src + sc*a) : LEAKY(sc*(a + sc*src));
        out[(size_t)gm*HD + gc] = o;
      }
    }
  }
}

// ---------------- split-bf16 MFMA linear: out = act(Ain @ W^T + bias) ----------------
// A: pre-split (Ah_/Al_, DMA-staged) or fp32 (Ain, in-kernel split w/ swizzled
// ds_write). W always pre-split, DMA-staged. 3 MFMA passes: ah*bh+al*bh+ah*bl.
// Outputs: fp32 (out!=null) and/or split bf16 hi/lo (outh!=null) for chaining.
// act 0: none, 1: leaky, 2: sinkhorn init (Z0 = (40*tanh(x)+gumbel)/0.1)
__global__ __launch_bounds__(512) void gemm_nt_mfma_k(const float* __restrict__ Ain,
                                                      const unsigned short* __restrict__ Ah_,
                                                      const unsigned short* __restrict__ Al_,
                                                      int lda,
                                                      const unsigned short* __restrict__ Wh_,
                                                      const unsigned short* __restrict__ Wl_,
                                                      const float* __restrict__ bias,
                                                      float* __restrict__ out, int ldo,
                                                      unsigned short* __restrict__ outh,
                                                      unsigned short* __restrict__ outl,
                                                      int K, int act){
  __shared__ unsigned short Ah[128][32], Al[128][32], Bh[128][32], Bl[128][32];
  int o0 = blockIdx.x*128, m0 = blockIdx.y*128;
  int tid = threadIdx.x;
  int wave = tid >> 6, lane = tid & 63;
  int quad = lane >> 4, l16 = lane & 15;
  int wr = (wave >> 2)*64;
  int wc = (wave & 3)*32;

  int r  = tid >> 2;
  int cg = (((tid & 3) ^ ((r >> 1) & 3)) << 3);
  int wbase = (tid >> 6) << 9;
  unsigned short* lAh = &Ah[0][0] + wbase;
  unsigned short* lAl = &Al[0][0] + wbase;
  unsigned short* lBh = &Bh[0][0] + wbase;
  unsigned short* lBl = &Bl[0][0] + wbase;
  const unsigned short* gWh = Wh_ + (size_t)(o0 + r)*K + cg;
  const unsigned short* gWl = Wl_ + (size_t)(o0 + r)*K + cg;
  const unsigned short* gAh = Ah_ ? Ah_ + (size_t)(m0 + r)*lda + cg : (const unsigned short*)0;
  const unsigned short* gAl = Ah_ ? Al_ + (size_t)(m0 + r)*lda + cg : (const unsigned short*)0;

  f32x4 acc[4][2] = {};

  for (int kc = 0; kc < K; kc += 32){
    GLL16(gWh + kc, lBh);
    GLL16(gWl + kc, lBl);
    if (Ah_){
      GLL16(gAh + kc, lAh);
      GLL16(gAl + kc, lAl);
    } else {
      #pragma unroll
      for (int it=0; it<2; it++){
        int f = tid + it*512;
        int rr = f >> 3, c4 = (f & 7)*4;
        float4 va = *(const float4*)(Ain + (size_t)(m0+rr)*lda + kc + c4);
        ushort4 h, lo;
        h.x = f2bf(va.x); lo.x = f2bf(va.x - bf2f(h.x));
        h.y = f2bf(va.y); lo.y = f2bf(va.y - bf2f(h.y));
        h.z = f2bf(va.z); lo.z = f2bf(va.z - bf2f(h.z));
        h.w = f2bf(va.w); lo.w = f2bf(va.w - bf2f(h.w));
        int sw = (((c4 >> 3) ^ ((rr >> 1) & 3)) << 3) | (c4 & 7);
        *(ushort4*)&Ah[rr][sw] = h;
        *(ushort4*)&Al[rr][sw] = lo;
      }
    }
    __syncthreads();
    short8 ahv[4], alv[4];
    #pragma unroll
    for (int rt=0; rt<4; rt++){
      int R = wr + rt*16 + l16;
      int sc = (quad ^ ((R >> 1) & 3)) << 3;
      ahv[rt] = *(const short8*)&Ah[R][sc];
      alv[rt] = *(const short8*)&Al[R][sc];
    }
    #pragma unroll
    for (int ct=0; ct<2; ct++){
      int Rb = wc + ct*16 + l16;
      int sc = (quad ^ ((Rb >> 1) & 3)) << 3;
      short8 bh = *(const short8*)&Bh[Rb][sc];
      short8 bl = *(const short8*)&Bl[Rb][sc];
      #pragma unroll
      for (int rt=0; rt<4; rt++){
        acc[rt][ct] = __builtin_amdgcn_mfma_f32_16x16x32_bf16(ahv[rt], bh, acc[rt][ct], 0, 0, 0);
        acc[rt][ct] = __builtin_amdgcn_mfma_f32_16x16x32_bf16(alv[rt], bh, acc[rt][ct], 0, 0, 0);
        acc[rt][ct] = __builtin_amdgcn_mfma_f32_16x16x32_bf16(ahv[rt], bl, acc[rt][ct], 0, 0, 0);
      }
    }
    __syncthreads();
  }

  #pragma unroll
  for (int rt=0; rt<4; rt++){
    #pragma unroll
    for (int p=0; p<4; p++){
      int gm = m0 + wr + rt*16 + quad*4 + p;
      #pragma unroll
      for (int ct=0; ct<2; ct++){
        int gc = o0 + wc + ct*16 + l16;
        float v = acc[rt][ct][p] + bias[gc];
        if (act == 1){
          v = LEAKY(v);
        } else if (act == 2){
          // fast tanh: clamp then (e^{2x}-1)/(e^{2x}+1); tanh(15)==1 in fp32
          float vcl = fminf(fmaxf(v, -15.f), 15.f);
          float e = __expf(2.f*vcl);
          float lg = 40.0f * (e - 1.f) / (e + 1.f);
          unsigned flat = (unsigned)gm*1024u + (unsigned)gc;
          v = (lg + gumbel_noise(flat)) / 0.1f;
        }
        if (out) out[(size_t)gm*ldo + gc] = v;
        if (outh){
          unsigned short hh = f2bf(v);
          outh[(size_t)gm*ldo + gc] = hh;
          outl[(size_t)gm*ldo + gc] = f2bf(v - bf2f(hh));
        }
      }
    }
  }
}

// ---------------- channel attention + combine (writes split bf16 hi/lo) ----------------
__global__ __launch_bounds__(256) void attn_k(const float* __restrict__ c0,
                                              const float* __restrict__ s0,
                                              const float* __restrict__ s1,
                                              const float* __restrict__ s2,
                                              const float* __restrict__ a2,
                                              unsigned short* __restrict__ outh,
                                              unsigned short* __restrict__ outl){
  int tid = threadIdx.x, wid = tid >> 6, lane = tid & 63;
  int row = blockIdx.x*4 + wid;
  size_t base = (size_t)row*HD + lane*4;
  float4 av = *(const float4*)(a2 + lane*4);
  float4 v[4];
  v[0] = *(const float4*)(c0 + base);
  v[1] = *(const float4*)(s0 + base);
  v[2] = *(const float4*)(s1 + base);
  v[3] = *(const float4*)(s2 + base);
  float e[4];
  #pragma unroll
  for (int c=0;c<4;c++){
    float p = fmaxf(v[c].x,0.f)*av.x + fmaxf(v[c].y,0.f)*av.y
            + fmaxf(v[c].z,0.f)*av.z + fmaxf(v[c].w,0.f)*av.w;
    e[c] = wave_sum(p);
  }
  float m = fmaxf(fmaxf(e[0],e[1]), fmaxf(e[2],e[3]));
  float w0 = expf(e[0]-m), w1 = expf(e[1]-m), w2 = expf(e[2]-m), w3 = expf(e[3]-m);
  float inv = 0.25f / (w0+w1+w2+w3);
  float4 o;
  o.x = (w0*v[0].x + w1*v[1].x + w2*v[2].x + w3*v[3].x)*inv;
  o.y = (w0*v[0].y + w1*v[1].y + w2*v[2].y + w3*v[3].y)*inv;
  o.z = (w0*v[0].z + w1*v[1].z + w2*v[2].z + w3*v[3].z)*inv;
  o.w = (w0*v[0].w + w1*v[1].w + w2*v[2].w + w3*v[3].w)*inv;
  ushort4 oh, ol;
  oh.x = f2bf(o.x); ol.x = f2bf(o.x - bf2f(oh.x));
  oh.y = f2bf(o.y); ol.y = f2bf(o.y - bf2f(oh.y));
  oh.z = f2bf(o.z); ol.z = f2bf(o.z - bf2f(oh.z));
  oh.w = f2bf(o.w); ol.w = f2bf(o.w - bf2f(oh.w));
  *(ushort4*)(outh + base) = oh;
  *(ushort4*)(outl + base) = ol;
}

// ---------------- batched 1024x1024 transpose ----------------
__global__ __launch_bounds__(256) void transpose_k(const float* __restrict__ Z,
                                                   float* __restrict__ Zt){
  __shared__ float tile[64][65];
  int bz = blockIdx.z;
  int i0 = blockIdx.y*64, j0 = blockIdx.x*64;
  const float* Zb = Z  + (size_t)bz*NN*NN;
  float*       Tb = Zt + (size_t)bz*NN*NN;
  int tid = threadIdx.x;
  #pragma unroll
  for (int it=0; it<4; it++){
    int f = tid + it*256;
    int r = f >> 4, c4 = (f & 15)*4;
    float4 v = *(const float4*)(Zb + (size_t)(i0+r)*NN + j0 + c4);
    tile[r][c4+0]=v.x; tile[r][c4+1]=v.y; tile[r][c4+2]=v.z; tile[r][c4+3]=v.w;
  }
  __syncthreads();
  #pragma unroll
  for (int it=0; it<4; it++){
    int f = tid + it*256;
    int r = f >> 4, c4 = (f & 15)*4;
    float4 v = make_float4(tile[c4+0][r], tile[c4+1][r], tile[c4+2][r], tile[c4+3][r]);
    *(float4*)(Tb + (size_t)(j0+r)*NN + i0 + c4) = v;
  }
}

// ---------------- sinkhorn passes (fast exp/log: rel err ~1e-6, BW-bound) ----------------
__global__ __launch_bounds__(256) void lse_rows_k(const float* __restrict__ Z,
                                                  const float* __restrict__ sub,
                                                  float* __restrict__ outv){
  __shared__ float redm[4], reds[4];
  int tid = threadIdx.x, wid = tid >> 6, lane = tid & 63;
  int row = blockIdx.x;
  int b = row >> 10;
  float4 z  = *(const float4*)(Z   + (size_t)row*NN + tid*4);
  float4 s4 = *(const float4*)(sub + (size_t)b*NN   + tid*4);
  float x0 = z.x - s4.x, x1 = z.y - s4.y, x2 = z.z - s4.z, x3 = z.w - s4.w;
  float m = fmaxf(fmaxf(x0,x1), fmaxf(x2,x3));
  m = wave_max(m);
  if (lane==0) redm[wid] = m;
  __syncthreads();
  float M = fmaxf(fmaxf(redm[0],redm[1]), fmaxf(redm[2],redm[3]));
  float s = __expf(x0-M) + __expf(x1-M) + __expf(x2-M) + __expf(x3-M);
  s = wave_sum(s);
  if (lane==0) reds[wid] = s;
  __syncthreads();
  if (tid==0) outv[row] = M + __logf(reds[0]+reds[1]+reds[2]+reds[3]);
}

__global__ __launch_bounds__(256) void sumexp_rows_k(const float* __restrict__ Zt,
                                                     const float* __restrict__ Lv,
                                                     const float* __restrict__ Cv,
                                                     float* __restrict__ Tv){
  __shared__ float reds[4];
  int tid = threadIdx.x, wid = tid >> 6, lane = tid & 63;
  int row = blockIdx.x;
  int b = row >> 10;
  float sc = Cv[row];
  float4 z  = *(const float4*)(Zt + (size_t)row*NN + tid*4);
  float4 l4 = *(const float4*)(Lv + (size_t)b*NN   + tid*4);
  float s = __expf(z.x - l4.x - sc) + __expf(z.y - l4.y - sc)
          + __expf(z.z - l4.z - sc) + __expf(z.w - l4.w - sc);
  s = wave_sum(s);
  if (lane==0) reds[wid] = s;
  __syncthreads();
  if (tid==0) Tv[row] = reds[0]+reds[1]+reds[2]+reds[3];
}

__global__ __launch_bounds__(256) void writep_k(const float* __restrict__ Z,
                                                const float* __restrict__ Cv,
                                                const float* __restrict__ Lv,
                                                const float* __restrict__ Tv,
                                                float* __restrict__ P){
  int gid = blockIdx.x*256 + threadIdx.x;
  int row = gid >> 8;
  int j = (gid & 255)*4;
  int b = row >> 10;
  float4 z = ((const float4*)Z)[gid];
  float4 c = *(const float4*)(Cv + (size_t)b*NN + j);
  float4 t = *(const float4*)(Tv + (size_t)b*NN + j);
  float l = Lv[row];
  float4 o;
  o.x = __expf(z.x - c.x - l) / t.x;
  o.y = __expf(z.y - c.y - l) / t.y;
  o.z = __expf(z.z - c.z - l) / t.z;
  o.w = __expf(z.w - c.w - l) / t.w;
  ((float4*)P)[gid] = o;
}

// ---------------- host orchestration ----------------
extern "C" void kernel_launch(void* const* d_in, const int* in_sizes, int n_in,
                              void* d_out, int out_size, void* d_ws, size_t ws_size,
                              hipStream_t stream){
  const float* X    = (const float*)d_in[0];
  const float* adj  = (const float*)d_in[1];
  const float* w_in = (const float*)d_in[2];
  const float* b_in = (const float*)d_in[3];
  const float* cw1  = (const float*)d_in[4];
  const float* cb1  = (const float*)d_in[5];
  const float* cw2  = (const float*)d_in[6];
  const float* cb2  = (const float*)d_in[7];
  const float* ca   = (const float*)d_in[8];
  const float* m1w  = (const float*)d_in[9];
  const float* m1b  = (const float*)d_in[10];
  const float* m2w  = (const float*)d_in[11];
  const float* m2b  = (const float*)d_in[12];

  float* outp = (float*)d_out;
  float* Pout = outp;                              // [0,16M) floats
  float* Z0   = outp + (size_t)16*1024*1024;       // [16M,32M) -> bytes [64,128)MB

  // d_out scratch slots (16 MiB each):
  //  slot0: X split (pre-inproj) -> s1 diffusion -> linear1 split (post-attn)
  //  slot1: s2 (C0) -> mlp1 split (post layer-2 attn)
  //  slot2: s3   slot3: s4 (t2) -> attn split   slot4: s5   slot5: s6
  //  slots6-7: adjbf (dead before mlp2's Z0 write finishes using them is fine:
  //            adjbf dead after last gemm_nn, Z0 spans slots 4-7)
  const size_t SLOT = (size_t)4*1024*1024;
  float* s1 = outp + 0*SLOT;
  float* s2 = outp + 1*SLOT;
  float* s3 = outp + 2*SLOT;
  float* s4 = outp + 3*SLOT;
  float* s5 = outp + 4*SLOT;
  float* s6 = outp + 5*SLOT;
  unsigned short* adjbf = (unsigned short*)(outp + 6*SLOT);   // 32 MiB

  unsigned short* Xh  = (unsigned short*)(outp + 0*SLOT);     // 4 MiB
  unsigned short* Xl  = Xh + (size_t)MROWS*IND;               // 4 MiB
  unsigned short* s4h = (unsigned short*)(outp + 3*SLOT);     // attn split: 8+8 MiB
  unsigned short* s4l = s4h + (size_t)MROWS*HD;
  unsigned short* l1h = (unsigned short*)(outp + 0*SLOT);     // linear1 split
  unsigned short* l1l = l1h + (size_t)MROWS*HD;
  unsigned short* m1sh = (unsigned short*)(outp + 1*SLOT);    // mlp1 split
  unsigned short* m1sl = m1sh + (size_t)MROWS*HD;

  float* ws     = (float*)d_ws;
  float* Zt     = ws;                                   // 16M floats (sinkhorn)
  float* hidden = ws;                                   // 12M floats (layers)
  float* dis    = ws + (size_t)12*1024*1024;
  float* rinv   = dis + 16384;
  unsigned short* bt = (unsigned short*)(rinv + 16384); // 8 MiB
  unsigned short* wsp = (unsigned short*)(ws + (size_t)15*1024*1024);
  unsigned short* winh = wsp;               unsigned short* winl = winh + 32768;
  unsigned short* w1h  = winl + 32768;      unsigned short* w1l  = w1h + 131072;
  unsigned short* w2h  = w1l + 131072;      unsigned short* w2l  = w2h + 131072;
  unsigned short* m1h  = w2l + 131072;      unsigned short* m1l  = m1h + 196608;
  unsigned short* m2h  = m1l + 196608;      unsigned short* m2l  = m2h + 262144;
  float* Rv = ws + (size_t)16*1024*1024;
  float* Cv = Rv + 16384;
  float* Lv = Cv + 16384;
  float* Tv = Lv + 16384;

  dim3 blk(256);
  dim3 gEw(4096);
  dim3 gMM(2, 8, 16);
  dim3 gCT(16, 4, 16);
  dim3 gRow(MROWS);

  adj_prep_k<<<gEw, blk, 0, stream>>>(adj, dis, rinv, adjbf);
  // pre-split weights + X (hi/lo bf16), one-time
  split_flat_k<<<dim3(32),  blk, 0, stream>>>(w_in, winh, winl, 8192);
  split_flat_k<<<dim3(128), blk, 0, stream>>>(cw1,  w1h,  w1l,  32768);
  split_flat_k<<<dim3(128), blk, 0, stream>>>(cw2,  w2h,  w2l,  32768);
  split_flat_k<<<dim3(192), blk, 0, stream>>>(m1w,  m1h,  m1l,  49152);
  split_flat_k<<<dim3(256), blk, 0, stream>>>(m2w,  m2h,  m2l,  65536);
  split_flat_k<<<dim3(2048), blk, 0, stream>>>(X, Xh, Xl, 524288);

  // input projection: hidden[:, 0:256] = X @ w_in^T + b_in
  gemm_nt_mfma_k<<<dim3(2,128), dim3(512), 0, stream>>>(nullptr, Xh, Xl, IND,
                                                        winh, winl, b_in,
                                                        hidden, 768, nullptr, nullptr,
                                                        IND, 0);

  for (int l=0; l<2; l++){
    const float* h_in = hidden + l*HD;       // ld 768
    unsigned short* wl1h = w1h + (size_t)l*65536;
    unsigned short* wl1l = w1l + (size_t)l*65536;
    unsigned short* wl2h = w2h + (size_t)l*65536;
    unsigned short* wl2l = w2l + (size_t)l*65536;
    const float* b1 = cb1 + (size_t)l*HD;
    const float* b2 = cb2 + (size_t)l*HD;
    const float* a2 = ca  + (size_t)l*2*HD + HD;   // x-part cancels in channel softmax

    // C0 = leaky(A_hat h)
    bconv_t_k<<<gCT, blk, 0, stream>>>(h_in, 768, dis, bt);
    gemm_nn_mfma_k<<<gMM, dim3(512), 0, stream>>>(adjbf, bt, h_in, 768, dis, s2, 2);
    // t1 = P h
    bconv_t_k<<<gCT, blk, 0, stream>>>(h_in, 768, nullptr, bt);
    gemm_nn_mfma_k<<<gMM, dim3(512), 0, stream>>>(adjbf, bt, h_in, 768, rinv, s1, 1);
    sub_abs_k<<<gEw, blk, 0, stream>>>(h_in, 768, s1, HD, s3);             // S0
    // t2 = P t1
    bconv_t_k<<<gCT, blk, 0, stream>>>(s1, HD, nullptr, bt);
    gemm_nn_mfma_k<<<gMM, dim3(512), 0, stream>>>(adjbf, bt, s1, HD, rinv, s4, 1);
    sub_abs_k<<<gEw, blk, 0, stream>>>(s1, HD, s4, HD, s5);                // S1
    // t3, t4
    bconv_t_k<<<gCT, blk, 0, stream>>>(s4, HD, nullptr, bt);
    gemm_nn_mfma_k<<<gMM, dim3(512), 0, stream>>>(adjbf, bt, s4, HD, rinv, s1, 1);
    bconv_t_k<<<gCT, blk, 0, stream>>>(s1, HD, nullptr, bt);
    gemm_nn_mfma_k<<<gMM, dim3(512), 0, stream>>>(adjbf, bt, s1, HD, rinv, s6, 1);
    sub_abs_k<<<gEw, blk, 0, stream>>>(s4, HD, s6, HD, s1);                // S2
    // attention combine -> split bf16 (slot3: t2 dead)
    attn_k<<<gEw, blk, 0, stream>>>(s2, s3, s5, s1, a2, s4h, s4l);
    // two linears; linear1 chains split output into linear2
    gemm_nt_mfma_k<<<dim3(2,128), dim3(512), 0, stream>>>(nullptr, s4h, s4l, HD,
                                                          wl1h, wl1l, b1,
                                                          nullptr, HD, l1h, l1l,
                                                          HD, 1);
    gemm_nt_mfma_k<<<dim3(2,128), dim3(512), 0, stream>>>(nullptr, l1h, l1l, HD,
                                                          wl2h, wl2l, b2,
                                                          hidden + (l+1)*HD, 768,
                                                          nullptr, nullptr, HD, 1);
  }

  // MLP head: mlp1 (fp32-A in-kernel split) -> split out -> mlp2 (act2)
  gemm_nt_mfma_k<<<dim3(2,128), dim3(512), 0, stream>>>(hidden, nullptr, nullptr, 768,
                                                        m1h, m1l, m1b,
                                                        nullptr, HD, m1sh, m1sl,
                                                        768, 1);
  gemm_nt_mfma_k<<<dim3(8,128), dim3(512), 0, stream>>>(nullptr, m1sh, m1sl, HD,
                                                        m2h, m2l, m2b,
                                                        Z0, OUTD, nullptr, nullptr,
                                                        HD, 2);

  // Sinkhorn: Z_t = Z0 - R_i - C_j (rank-1 log-space; Z0 read-only)
  transpose_k<<<dim3(16,16,16), blk, 0, stream>>>(Z0, Zt);
  hipMemsetAsync(Cv, 0, MROWS*sizeof(float), stream);
  for (int t=0; t<20; t++){
    lse_rows_k<<<gRow, blk, 0, stream>>>(Z0, Cv, Rv);
    lse_rows_k<<<gRow, blk, 0, stream>>>(Zt, Rv, Cv);
  }
  lse_rows_k<<<gRow, blk, 0, stream>>>(Z0, Cv, Lv);
  sumexp_rows_k<<<gRow, blk, 0, stream>>>(Zt, Lv, Cv, Tv);
  writep_k<<<gRow, blk, 0, stream>>>(Z0, Cv, Lv, Tv, Pout);
}

// Round 2
// 1208.403 us; speedup vs baseline: 1.2481x; 1.1834x over previous
//
#include <hip/hip_runtime.h>
#include <cstdint>
#include <cstddef>

// Problem constants
#define BB 16
#define NN 1024
#define HD 256
#define IND 128
#define OUTD 1024
#define MROWS (BB*NN)          // 16384

#define LEAKY(x) ((x) >= 0.0f ? (x) : 0.01f*(x))

typedef short short8 __attribute__((ext_vector_type(8)));
typedef float f32x4 __attribute__((ext_vector_type(4)));

// 16B async global->LDS DMA. LDS dest is wave-uniform base + lane*16 (linear);
// swizzling is done on the GLOBAL source address + on the ds_read side (same
// XOR involution both sides).
#define GLL16(gsrc, ldst) __builtin_amdgcn_global_load_lds( \
    (const __attribute__((address_space(1))) unsigned int*)(gsrc), \
    (__attribute__((address_space(3))) unsigned int*)(ldst), 16, 0, 0)

// ---------------- wave helpers ----------------
__device__ inline float wave_sum(float v){
  #pragma unroll
  for (int off=32; off; off>>=1) v += __shfl_xor(v, off, 64);
  return v;
}
__device__ inline float wave_max(float v){
  #pragma unroll
  for (int off=32; off; off>>=1) v = fmaxf(v, __shfl_xor(v, off, 64));
  return v;
}

// fp32 -> bf16 round-to-nearest-even; bf16 -> fp32
__device__ inline unsigned short f2bf(float x){
  unsigned u = __float_as_uint(x);
  unsigned r = (u + 0x7fffu + ((u >> 16) & 1u)) >> 16;
  return (unsigned short)r;
}
__device__ inline float bf2f(unsigned short h){
  return __uint_as_float((unsigned)h << 16);
}

// ---------------- JAX threefry2x32 gumbel noise (partitionable) ----------------
// __logf: v_log based; abs error on final Z0 ~1e-3 << tolerance.
__device__ inline float gumbel_noise(unsigned m){
  const unsigned k0 = 0u, k1 = 42u;
  const unsigned ks2 = k0 ^ k1 ^ 0x1BD11BDAu;
  unsigned x0 = 0u, x1 = m;
  x0 += k0; x1 += k1;
  #define TF_ROUND(r) { x0 += x1; x1 = (x1 << (r)) | (x1 >> (32-(r))); x1 ^= x0; }
  TF_ROUND(13) TF_ROUND(15) TF_ROUND(26) TF_ROUND(6)
  x0 += k1;  x1 += ks2 + 1u;
  TF_ROUND(17) TF_ROUND(29) TF_ROUND(16) TF_ROUND(24)
  x0 += ks2; x1 += k0 + 2u;
  TF_ROUND(13) TF_ROUND(15) TF_ROUND(26) TF_ROUND(6)
  x0 += k0;  x1 += k1 + 3u;
  TF_ROUND(17) TF_ROUND(29) TF_ROUND(16) TF_ROUND(24)
  x0 += k1;  x1 += ks2 + 4u;
  TF_ROUND(13) TF_ROUND(15) TF_ROUND(26) TF_ROUND(6)
  x0 += ks2; x1 += k0 + 5u;
  #undef TF_ROUND
  unsigned bits = x0 ^ x1;
  float u = __uint_as_float((bits >> 9) | 0x3f800000u) - 1.0f;   // [0,1)
  float t = -__logf(u + 1e-20f);
  return -__logf(t + 1e-20f) * 0.05f;   // NOISE_SCALE
}

// ---------------- fused adj row stats + bf16 convert ----------------
__global__ __launch_bounds__(256) void adj_prep_k(const float* __restrict__ adj,
                                                  float* __restrict__ dis,
                                                  float* __restrict__ rinv,
                                                  unsigned short* __restrict__ abf){
  int tid = threadIdx.x, wid = tid >> 6, lane = tid & 63;
  int row = blockIdx.x*4 + wid;
  const float4* rp = (const float4*)(adj + (size_t)row*NN);
  ushort4* op = (ushort4*)(abf + (size_t)row*NN);
  float s = 0.f;
  #pragma unroll
  for (int p=0;p<4;p++){
    float4 v = rp[lane + p*64];
    s += v.x+v.y+v.z+v.w;
    ushort4 o;
    o.x = f2bf(v.x); o.y = f2bf(v.y); o.z = f2bf(v.z); o.w = f2bf(v.w);
    op[lane + p*64] = o;
  }
  s = wave_sum(s);
  if (lane==0){
    dis[row]  = 1.0f/sqrtf(s + 1.0f);
    rinv[row] = 1.0f/s;
  }
}

// ---------------- flat hi/lo split (weights, X) ----------------
__global__ __launch_bounds__(256) void split_flat_k(const float* __restrict__ src,
                                                    unsigned short* __restrict__ h,
                                                    unsigned short* __restrict__ l,
                                                    int n4){
  int gid = blockIdx.x*256 + threadIdx.x;
  if (gid >= n4) return;
  float4 v = ((const float4*)src)[gid];
  ushort4 hh, ll;
  hh.x = f2bf(v.x); ll.x = f2bf(v.x - bf2f(hh.x));
  hh.y = f2bf(v.y); ll.y = f2bf(v.y - bf2f(hh.y));
  hh.z = f2bf(v.z); ll.z = f2bf(v.z - bf2f(hh.z));
  hh.w = f2bf(v.w); ll.w = f2bf(v.w - bf2f(hh.w));
  ((ushort4*)h)[gid] = hh;
  ((ushort4*)l)[gid] = ll;
}

// fp32 [16][1024 i][ld] (cols 0..255) -> bf16 transposed [16][256 c][1024 i]
__global__ __launch_bounds__(256) void bconv_t_k(const float* __restrict__ in, int ld,
                                                 const float* __restrict__ scale,
                                                 unsigned short* __restrict__ outT){
  __shared__ float tile[64][68];
  int b  = blockIdx.z;
  int i0 = blockIdx.x*64;
  int c0 = blockIdx.y*64;
  const float* inb = in + (size_t)b*NN*ld;
  unsigned short* ob = outT + (size_t)b*HD*NN;
  int tid = threadIdx.x;
  #pragma unroll
  for (int it=0; it<4; it++){
    int f = tid + it*256;
    int r = f >> 4, c4 = (f & 15)*4;
    float4 v = *(const float4*)(inb + (size_t)(i0+r)*ld + c0 + c4);
    float s = scale ? scale[b*NN + i0 + r] : 1.0f;
    tile[r][c4+0]=v.x*s; tile[r][c4+1]=v.y*s; tile[r][c4+2]=v.z*s; tile[r][c4+3]=v.w*s;
  }
  __syncthreads();
  #pragma unroll
  for (int it=0; it<4; it++){
    int f = tid + it*256;
    int cl = f >> 4, r4 = (f & 15)*4;
    ushort4 o;
    o.x = f2bf(tile[r4+0][cl]);
    o.y = f2bf(tile[r4+1][cl]);
    o.z = f2bf(tile[r4+2][cl]);
    o.w = f2bf(tile[r4+3][cl]);
    *(ushort4*)(ob + (size_t)(c0+cl)*NN + i0 + r4) = o;
  }
}

// ---------------- MFMA batched GEMM: acc = adj[b] @ B[b] ----------------
// DMA staging + XOR slot-swizzle (2-way conflicts, free).
// mode 1: o = 0.5*(Bsrc[i][n] + sc_i*acc)
// mode 2: o = leaky(sc_i*(acc + sc_i*Bsrc[i][n]))
// out  (optional): o
// out2 (optional): |(sub ? sub : Bsrc) - o|   (fused scattering sub_abs)
__global__ __launch_bounds__(512) void gemm_nn_mfma_k(const unsigned short* __restrict__ Abf,
                                                      const unsigned short* __restrict__ Btb,
                                                      const float* __restrict__ Bsrc, int ldb,
                                                      const float* __restrict__ rowscale,
                                                      float* __restrict__ out,
                                                      float* __restrict__ out2,
                                                      const float* __restrict__ sub,
                                                      int mode){
  __shared__ unsigned short Als[128][32];
  __shared__ unsigned short Bls[128][32];
  int b  = blockIdx.z;
  int n0 = blockIdx.x*128;
  int i0 = blockIdx.y*128;
  const unsigned short* Ab = Abf + (size_t)b*NN*NN + (size_t)i0*NN;
  const unsigned short* Bb = Btb + (size_t)b*HD*NN + (size_t)n0*NN;
  int tid = threadIdx.x;
  int wave = tid >> 6, lane = tid & 63;
  int quad = lane >> 4, l16 = lane & 15;
  int wr = (wave >> 2)*64;
  int wc = (wave & 3)*32;

  int r  = tid >> 2;
  int cg = (((tid & 3) ^ ((r >> 1) & 3)) << 3);
  int wbase = (tid >> 6) << 9;
  unsigned short* lA = &Als[0][0] + wbase;
  unsigned short* lB = &Bls[0][0] + wbase;
  const unsigned short* gA = Ab + (size_t)r*NN + cg;
  const unsigned short* gB = Bb + (size_t)r*NN + cg;

  f32x4 acc[4][2] = {};

  for (int kc = 0; kc < NN; kc += 32){
    GLL16(gA + kc, lA);
    GLL16(gB + kc, lB);
    __syncthreads();
    short8 af[4];
    #pragma unroll
    for (int rt=0; rt<4; rt++){
      int R = wr + rt*16 + l16;
      af[rt] = *(const short8*)&Als[R][(quad ^ ((R >> 1) & 3)) << 3];
    }
    #pragma unroll
    for (int ct=0; ct<2; ct++){
      int Rb = wc + ct*16 + l16;
      short8 bfr = *(const short8*)&Bls[Rb][(quad ^ ((Rb >> 1) & 3)) << 3];
      #pragma unroll
      for (int rt=0; rt<4; rt++)
        acc[rt][ct] = __builtin_amdgcn_mfma_f32_16x16x32_bf16(af[rt], bfr, acc[rt][ct], 0, 0, 0);
    }
    __syncthreads();
  }

  #pragma unroll
  for (int rt=0; rt<4; rt++){
    #pragma unroll
    for (int p=0; p<4; p++){
      int gr = i0 + wr + rt*16 + quad*4 + p;
      int gm = b*NN + gr;
      float sc = rowscale[gm];
      #pragma unroll
      for (int ct=0; ct<2; ct++){
        int gc = n0 + wc + ct*16 + l16;
        float a = acc[rt][ct][p];
        float src = Bsrc[(size_t)gm*ldb + gc];
        float o = (mode == 1) ? 0.5f*(src + sc*a) : LEAKY(sc*(a + sc*src));
        if (out) out[(size_t)gm*HD + gc] = o;
        if (out2){
          float sv = sub ? sub[(size_t)gm*HD + gc] : src;
          out2[(size_t)gm*HD + gc] = fabsf(sv - o);
        }
      }
    }
  }
}

// ---------------- split-bf16 MFMA linear: out = act(Ain @ W^T + bias) ----------------
// act 0: none, 1: leaky, 2: sinkhorn init (Z0 = (40*tanh(x)+gumbel)/0.1)
__global__ __launch_bounds__(512) void gemm_nt_mfma_k(const float* __restrict__ Ain,
                                                      const unsigned short* __restrict__ Ah_,
                                                      const unsigned short* __restrict__ Al_,
                                                      int lda,
                                                      const unsigned short* __restrict__ Wh_,
                                                      const unsigned short* __restrict__ Wl_,
                                                      const float* __restrict__ bias,
                                                      float* __restrict__ out, int ldo,
                                                      unsigned short* __restrict__ outh,
                                                      unsigned short* __restrict__ outl,
                                                      int K, int act){
  __shared__ unsigned short Ah[128][32], Al[128][32], Bh[128][32], Bl[128][32];
  int o0 = blockIdx.x*128, m0 = blockIdx.y*128;
  int tid = threadIdx.x;
  int wave = tid >> 6, lane = tid & 63;
  int quad = lane >> 4, l16 = lane & 15;
  int wr = (wave >> 2)*64;
  int wc = (wave & 3)*32;

  int r  = tid >> 2;
  int cg = (((tid & 3) ^ ((r >> 1) & 3)) << 3);
  int wbase = (tid >> 6) << 9;
  unsigned short* lAh = &Ah[0][0] + wbase;
  unsigned short* lAl = &Al[0][0] + wbase;
  unsigned short* lBh = &Bh[0][0] + wbase;
  unsigned short* lBl = &Bl[0][0] + wbase;
  const unsigned short* gWh = Wh_ + (size_t)(o0 + r)*K + cg;
  const unsigned short* gWl = Wl_ + (size_t)(o0 + r)*K + cg;
  const unsigned short* gAh = Ah_ ? Ah_ + (size_t)(m0 + r)*lda + cg : (const unsigned short*)0;
  const unsigned short* gAl = Ah_ ? Al_ + (size_t)(m0 + r)*lda + cg : (const unsigned short*)0;

  f32x4 acc[4][2] = {};

  for (int kc = 0; kc < K; kc += 32){
    GLL16(gWh + kc, lBh);
    GLL16(gWl + kc, lBl);
    if (Ah_){
      GLL16(gAh + kc, lAh);
      GLL16(gAl + kc, lAl);
    } else {
      #pragma unroll
      for (int it=0; it<2; it++){
        int f = tid + it*512;
        int rr = f >> 3, c4 = (f & 7)*4;
        float4 va = *(const float4*)(Ain + (size_t)(m0+rr)*lda + kc + c4);
        ushort4 h, lo;
        h.x = f2bf(va.x); lo.x = f2bf(va.x - bf2f(h.x));
        h.y = f2bf(va.y); lo.y = f2bf(va.y - bf2f(h.y));
        h.z = f2bf(va.z); lo.z = f2bf(va.z - bf2f(h.z));
        h.w = f2bf(va.w); lo.w = f2bf(va.w - bf2f(h.w));
        int sw = (((c4 >> 3) ^ ((rr >> 1) & 3)) << 3) | (c4 & 7);
        *(ushort4*)&Ah[rr][sw] = h;
        *(ushort4*)&Al[rr][sw] = lo;
      }
    }
    __syncthreads();
    short8 ahv[4], alv[4];
    #pragma unroll
    for (int rt=0; rt<4; rt++){
      int R = wr + rt*16 + l16;
      int sc = (quad ^ ((R >> 1) & 3)) << 3;
      ahv[rt] = *(const short8*)&Ah[R][sc];
      alv[rt] = *(const short8*)&Al[R][sc];
    }
    #pragma unroll
    for (int ct=0; ct<2; ct++){
      int Rb = wc + ct*16 + l16;
      int sc = (quad ^ ((Rb >> 1) & 3)) << 3;
      short8 bh = *(const short8*)&Bh[Rb][sc];
      short8 bl = *(const short8*)&Bl[Rb][sc];
      #pragma unroll
      for (int rt=0; rt<4; rt++){
        acc[rt][ct] = __builtin_amdgcn_mfma_f32_16x16x32_bf16(ahv[rt], bh, acc[rt][ct], 0, 0, 0);
        acc[rt][ct] = __builtin_amdgcn_mfma_f32_16x16x32_bf16(alv[rt], bh, acc[rt][ct], 0, 0, 0);
        acc[rt][ct] = __builtin_amdgcn_mfma_f32_16x16x32_bf16(ahv[rt], bl, acc[rt][ct], 0, 0, 0);
      }
    }
    __syncthreads();
  }

  #pragma unroll
  for (int rt=0; rt<4; rt++){
    #pragma unroll
    for (int p=0; p<4; p++){
      int gm = m0 + wr + rt*16 + quad*4 + p;
      #pragma unroll
      for (int ct=0; ct<2; ct++){
        int gc = o0 + wc + ct*16 + l16;
        float v = acc[rt][ct][p] + bias[gc];
        if (act == 1){
          v = LEAKY(v);
        } else if (act == 2){
          // fast tanh: clamp then (e^{2x}-1)/(e^{2x}+1); tanh(15)==1 in fp32
          float vcl = fminf(fmaxf(v, -15.f), 15.f);
          float e = __expf(2.f*vcl);
          float lg = 40.0f * (e - 1.f) / (e + 1.f);
          unsigned flat = (unsigned)gm*1024u + (unsigned)gc;
          v = (lg + gumbel_noise(flat)) / 0.1f;
        }
        if (out) out[(size_t)gm*ldo + gc] = v;
        if (outh){
          unsigned short hh = f2bf(v);
          outh[(size_t)gm*ldo + gc] = hh;
          outl[(size_t)gm*ldo + gc] = f2bf(v - bf2f(hh));
        }
      }
    }
  }
}

// ---------------- channel attention + combine (writes split bf16 hi/lo) ----------------
__global__ __launch_bounds__(256) void attn_k(const float* __restrict__ c0,
                                              const float* __restrict__ s0,
                                              const float* __restrict__ s1,
                                              const float* __restrict__ s2,
                                              const float* __restrict__ a2,
                                              unsigned short* __restrict__ outh,
                                              unsigned short* __restrict__ outl){
  int tid = threadIdx.x, wid = tid >> 6, lane = tid & 63;
  int row = blockIdx.x*4 + wid;
  size_t base = (size_t)row*HD + lane*4;
  float4 av = *(const float4*)(a2 + lane*4);
  float4 v[4];
  v[0] = *(const float4*)(c0 + base);
  v[1] = *(const float4*)(s0 + base);
  v[2] = *(const float4*)(s1 + base);
  v[3] = *(const float4*)(s2 + base);
  float e[4];
  #pragma unroll
  for (int c=0;c<4;c++){
    float p = fmaxf(v[c].x,0.f)*av.x + fmaxf(v[c].y,0.f)*av.y
            + fmaxf(v[c].z,0.f)*av.z + fmaxf(v[c].w,0.f)*av.w;
    e[c] = wave_sum(p);
  }
  float m = fmaxf(fmaxf(e[0],e[1]), fmaxf(e[2],e[3]));
  float w0 = expf(e[0]-m), w1 = expf(e[1]-m), w2 = expf(e[2]-m), w3 = expf(e[3]-m);
  float inv = 0.25f / (w0+w1+w2+w3);
  float4 o;
  o.x = (w0*v[0].x + w1*v[1].x + w2*v[2].x + w3*v[3].x)*inv;
  o.y = (w0*v[0].y + w1*v[1].y + w2*v[2].y + w3*v[3].y)*inv;
  o.z = (w0*v[0].z + w1*v[1].z + w2*v[2].z + w3*v[3].z)*inv;
  o.w = (w0*v[0].w + w1*v[1].w + w2*v[2].w + w3*v[3].w)*inv;
  ushort4 oh, ol;
  oh.x = f2bf(o.x); ol.x = f2bf(o.x - bf2f(oh.x));
  oh.y = f2bf(o.y); ol.y = f2bf(o.y - bf2f(oh.y));
  oh.z = f2bf(o.z); ol.z = f2bf(o.z - bf2f(oh.z));
  oh.w = f2bf(o.w); ol.w = f2bf(o.w - bf2f(oh.w));
  *(ushort4*)(outh + base) = oh;
  *(ushort4*)(outl + base) = ol;
}

// ================= linear-domain Sinkhorn =================
// E_ij = exp(Z0_ij - alpha_i - beta_j), alpha = rowmax(Z0),
// beta_j = colmax(Z0 - alpha). E in [0,1]; every row AND col has an exact 1.
// Iterate a = 1/(E b), b = 1/(E^T a)  (log-domain LSE passes, linearized).
// Final: a' = 1/(E b), t' = E^T a', P = E * a' / t'  (b cancels exactly).

__global__ __launch_bounds__(256) void rowmax_k(const float* __restrict__ Z,
                                                float* __restrict__ alpha){
  int tid = threadIdx.x, wid = tid >> 6, lane = tid & 63;
  int row = blockIdx.x*4 + wid;
  const float4* rp = (const float4*)(Z + (size_t)row*NN);
  float m = -3.4e38f;
  #pragma unroll
  for (int p=0;p<4;p++){
    float4 v = rp[lane + p*64];
    m = fmaxf(m, fmaxf(fmaxf(v.x,v.y), fmaxf(v.z,v.w)));
  }
  m = wave_max(m);
  if (lane==0) alpha[row] = m;
}

// partial colmax over 32-row chunks: pmax[b][chunk][j]
__global__ __launch_bounds__(256) void colmax_k(const float* __restrict__ Z,
                                                const float* __restrict__ alpha,
                                                float* __restrict__ pmax){
  int b = blockIdx.y, rc = blockIdx.x;
  int j = threadIdx.x*4;
  const float* Zb = Z + (size_t)b*NN*NN;
  const float* ab = alpha + b*NN;
  float4 m = make_float4(-3.4e38f,-3.4e38f,-3.4e38f,-3.4e38f);
  int r0 = rc*32;
  #pragma unroll 4
  for (int r=r0; r<r0+32; r++){
    float4 v = *(const float4*)(Zb + (size_t)r*NN + j);
    float a = ab[r];
    m.x = fmaxf(m.x, v.x-a); m.y = fmaxf(m.y, v.y-a);
    m.z = fmaxf(m.z, v.z-a); m.w = fmaxf(m.w, v.w-a);
  }
  *(float4*)(pmax + ((size_t)b*32 + rc)*NN + j) = m;
}

__global__ __launch_bounds__(256) void colred_k(const float* __restrict__ pmax,
                                                float* __restrict__ beta){
  int b = blockIdx.y;
  int j = blockIdx.x*256 + threadIdx.x;
  float m = -3.4e38f;
  #pragma unroll
  for (int rc=0; rc<32; rc++)
    m = fmaxf(m, pmax[((size_t)b*32+rc)*NN + j]);
  beta[b*NN + j] = m;
}

// build E (bf16 row-major) and E^T (bf16), consistent rounding
__global__ __launch_bounds__(256) void build_e_k(const float* __restrict__ Z,
                                                 const float* __restrict__ alpha,
                                                 const float* __restrict__ beta,
                                                 unsigned short* __restrict__ E,
                                                 unsigned short* __restrict__ Et){
  __shared__ float tile[64][65];
  int b = blockIdx.z;
  int i0 = blockIdx.y*64, j0 = blockIdx.x*64;
  const float* Zb = Z + (size_t)b*NN*NN;
  const float* ab = alpha + b*NN;
  const float* bb = beta  + b*NN;
  unsigned short* Eb  = E  + (size_t)b*NN*NN;
  unsigned short* Etb = Et + (size_t)b*NN*NN;
  int tid = threadIdx.x;
  #pragma unroll
  for (int it=0; it<4; it++){
    int f = tid + it*256;
    int r = f >> 4, c4 = (f & 15)*4;
    float4 v = *(const float4*)(Zb + (size_t)(i0+r)*NN + j0 + c4);
    float a = ab[i0+r];
    float e0 = __expf(v.x - a - bb[j0+c4+0]);
    float e1 = __expf(v.y - a - bb[j0+c4+1]);
    float e2 = __expf(v.z - a - bb[j0+c4+2]);
    float e3 = __expf(v.w - a - bb[j0+c4+3]);
    tile[r][c4+0]=e0; tile[r][c4+1]=e1; tile[r][c4+2]=e2; tile[r][c4+3]=e3;
    ushort4 o; o.x=f2bf(e0); o.y=f2bf(e1); o.z=f2bf(e2); o.w=f2bf(e3);
    *(ushort4*)(Eb + (size_t)(i0+r)*NN + j0 + c4) = o;
  }
  __syncthreads();
  #pragma unroll
  for (int it=0; it<4; it++){
    int f = tid + it*256;
    int r = f >> 4, c4 = (f & 15)*4;
    ushort4 o;
    o.x = f2bf(tile[c4+0][r]);
    o.y = f2bf(tile[c4+1][r]);
    o.z = f2bf(tile[c4+2][r]);
    o.w = f2bf(tile[c4+3][r]);
    *(ushort4*)(Etb + (size_t)(j0+r)*NN + i0 + c4) = o;
  }
}

// w[row] = (recip ? 1/ : ) sum_j M[row][j] * v[b][j]; v==null -> v=1
__global__ __launch_bounds__(256) void mv_k(const unsigned short* __restrict__ M,
                                            const float* __restrict__ v,
                                            float* __restrict__ w, int recip){
  int tid = threadIdx.x, wid = tid >> 6, lane = tid & 63;
  int row = blockIdx.x*4 + wid;
  int b = row >> 10;
  const unsigned short* mp = M + (size_t)row*NN + lane*16;
  float s = 0.f;
  if (v){
    const float* vb = v + b*NN + lane*16;
    #pragma unroll
    for (int h2=0; h2<2; h2++){
      short8 m8 = *(const short8*)(mp + h2*8);
      float4 v0 = *(const float4*)(vb + h2*8);
      float4 v1 = *(const float4*)(vb + h2*8 + 4);
      s += bf2f((unsigned short)m8[0])*v0.x + bf2f((unsigned short)m8[1])*v0.y
         + bf2f((unsigned short)m8[2])*v0.z + bf2f((unsigned short)m8[3])*v0.w
         + bf2f((unsigned short)m8[4])*v1.x + bf2f((unsigned short)m8[5])*v1.y
         + bf2f((unsigned short)m8[6])*v1.z + bf2f((unsigned short)m8[7])*v1.w;
    }
  } else {
    #pragma unroll
    for (int h2=0; h2<2; h2++){
      short8 m8 = *(const short8*)(mp + h2*8);
      #pragma unroll
      for (int q=0;q<8;q++) s += bf2f((unsigned short)m8[q]);
    }
  }
  s = wave_sum(s);
  if (lane==0) w[row] = recip ? 1.0f/s : s;
}

// P_ij = E_ij * a'_i / t'_j
__global__ __launch_bounds__(256) void writep_lin_k(const unsigned short* __restrict__ E,
                                                    const float* __restrict__ ap,
                                                    const float* __restrict__ tp,
                                                    float* __restrict__ P){
  int gid = blockIdx.x*256 + threadIdx.x;
  int row = gid >> 8;
  int j = (gid & 255)*4;
  int b = row >> 10;
  ushort4 e = ((const ushort4*)E)[gid];
  float a = ap[row];
  float4 t = *(const float4*)(tp + (size_t)b*NN + j);
  float4 o;
  o.x = bf2f(e.x)*a/t.x;
  o.y = bf2f(e.y)*a/t.y;
  o.z = bf2f(e.z)*a/t.z;
  o.w = bf2f(e.w)*a/t.w;
  ((float4*)P)[gid] = o;
}

// ---------------- host orchestration ----------------
extern "C" void kernel_launch(void* const* d_in, const int* in_sizes, int n_in,
                              void* d_out, int out_size, void* d_ws, size_t ws_size,
                              hipStream_t stream){
  const float* X    = (const float*)d_in[0];
  const float* adj  = (const float*)d_in[1];
  const float* w_in = (const float*)d_in[2];
  const float* b_in = (const float*)d_in[3];
  const float* cw1  = (const float*)d_in[4];
  const float* cb1  = (const float*)d_in[5];
  const float* cw2  = (const float*)d_in[6];
  const float* cb2  = (const float*)d_in[7];
  const float* ca   = (const float*)d_in[8];
  const float* m1w  = (const float*)d_in[9];
  const float* m1b  = (const float*)d_in[10];
  const float* m2w  = (const float*)d_in[11];
  const float* m2b  = (const float*)d_in[12];

  float* outp = (float*)d_out;
  float* Pout = outp;                              // [0,16M) floats
  float* Z0   = outp + (size_t)16*1024*1024;       // [16M,32M)

  const size_t SLOT = (size_t)4*1024*1024;
  float* s1 = outp + 0*SLOT;
  float* s2 = outp + 1*SLOT;
  float* s3 = outp + 2*SLOT;
  float* s4 = outp + 3*SLOT;
  float* s5 = outp + 4*SLOT;
  float* s6 = outp + 5*SLOT;
  unsigned short* adjbf = (unsigned short*)(outp + 6*SLOT);   // 32 MiB

  unsigned short* Xh  = (unsigned short*)(outp + 0*SLOT);
  unsigned short* Xl  = Xh + (size_t)MROWS*IND;
  unsigned short* s4h = (unsigned short*)(outp + 3*SLOT);
  unsigned short* s4l = s4h + (size_t)MROWS*HD;
  unsigned short* l1h = (unsigned short*)(outp + 0*SLOT);
  unsigned short* l1l = l1h + (size_t)MROWS*HD;
  unsigned short* m1sh = (unsigned short*)(outp + 1*SLOT);
  unsigned short* m1sl = m1sh + (size_t)MROWS*HD;
  // sinkhorn stabilizers in slot 0 (dead before P write)
  float* alpha = s1;                 // 64 KB
  float* beta  = s1 + 16384;         // 64 KB
  float* pmaxb = s1 + 32768;         // 2 MB (16*32*1024)

  float* ws     = (float*)d_ws;
  float* hidden = ws;                                   // 12M floats (layers)
  float* dis    = ws + (size_t)12*1024*1024;
  float* rinv   = dis + 16384;
  unsigned short* bt = (unsigned short*)(rinv + 16384); // 8 MiB
  unsigned short* wsp = (unsigned short*)(ws + (size_t)15*1024*1024);
  unsigned short* winh = wsp;               unsigned short* winl = winh + 32768;
  unsigned short* w1h  = winl + 32768;      unsigned short* w1l  = w1h + 131072;
  unsigned short* w2h  = w1l + 131072;      unsigned short* w2l  = w2h + 131072;
  unsigned short* m1h  = w2l + 131072;      unsigned short* m1l  = m1h + 196608;
  unsigned short* m2h  = m1l + 196608;      unsigned short* m2l  = m2h + 262144;
  // sinkhorn E / E^T occupy ws[0,64MiB) (hidden/weights dead by then)
  unsigned short* E  = (unsigned short*)ws;             // 32 MiB
  unsigned short* Et = E + (size_t)MROWS*NN;            // 32 MiB
  float* av = ws + (size_t)16*1024*1024;
  float* bv = av + 16384;
  float* tv = bv + 16384;

  dim3 blk(256);
  dim3 gEw(4096);
  dim3 gMM(2, 8, 16);
  dim3 gCT(16, 4, 16);

  adj_prep_k<<<gEw, blk, 0, stream>>>(adj, dis, rinv, adjbf);
  split_flat_k<<<dim3(32),  blk, 0, stream>>>(w_in, winh, winl, 8192);
  split_flat_k<<<dim3(128), blk, 0, stream>>>(cw1,  w1h,  w1l,  32768);
  split_flat_k<<<dim3(128), blk, 0, stream>>>(cw2,  w2h,  w2l,  32768);
  split_flat_k<<<dim3(192), blk, 0, stream>>>(m1w,  m1h,  m1l,  49152);
  split_flat_k<<<dim3(256), blk, 0, stream>>>(m2w,  m2h,  m2l,  65536);
  split_flat_k<<<dim3(2048), blk, 0, stream>>>(X, Xh, Xl, 524288);

  // input projection
  gemm_nt_mfma_k<<<dim3(2,128), dim3(512), 0, stream>>>(nullptr, Xh, Xl, IND,
                                                        winh, winl, b_in,
                                                        hidden, 768, nullptr, nullptr,
                                                        IND, 0);

  for (int l=0; l<2; l++){
    const float* h_in = hidden + l*HD;       // ld 768
    unsigned short* wl1h = w1h + (size_t)l*65536;
    unsigned short* wl1l = w1l + (size_t)l*65536;
    unsigned short* wl2h = w2h + (size_t)l*65536;
    unsigned short* wl2l = w2l + (size_t)l*65536;
    const float* b1 = cb1 + (size_t)l*HD;
    const float* b2 = cb2 + (size_t)l*HD;
    const float* a2 = ca  + (size_t)l*2*HD + HD;

    // C0 = leaky(A_hat h)
    bconv_t_k<<<gCT, blk, 0, stream>>>(h_in, 768, dis, bt);
    gemm_nn_mfma_k<<<gMM, dim3(512), 0, stream>>>(adjbf, bt, h_in, 768, dis, s2, nullptr, nullptr, 2);
    // t1 = P h ; S0 = |h - t1| (fused)
    bconv_t_k<<<gCT, blk, 0, stream>>>(h_in, 768, nullptr, bt);
    gemm_nn_mfma_k<<<gMM, dim3(512), 0, stream>>>(adjbf, bt, h_in, 768, rinv, s1, s3, nullptr, 1);
    // t2 = P t1 ; S1 = |t1 - t2| (fused)
    bconv_t_k<<<gCT, blk, 0, stream>>>(s1, HD, nullptr, bt);
    gemm_nn_mfma_k<<<gMM, dim3(512), 0, stream>>>(adjbf, bt, s1, HD, rinv, s4, s5, nullptr, 1);
    // t3 = P t2
    bconv_t_k<<<gCT, blk, 0, stream>>>(s4, HD, nullptr, bt);
    gemm_nn_mfma_k<<<gMM, dim3(512), 0, stream>>>(adjbf, bt, s4, HD, rinv, s1, nullptr, nullptr, 1);
    // t4 = P t3 ; S2 = |t2 - t4| (fused, t4 itself discarded)
    bconv_t_k<<<gCT, blk, 0, stream>>>(s1, HD, nullptr, bt);
    gemm_nn_mfma_k<<<gMM, dim3(512), 0, stream>>>(adjbf, bt, s1, HD, rinv, nullptr, s1, s4, 1);
    // attention combine -> split bf16
    attn_k<<<gEw, blk, 0, stream>>>(s2, s3, s5, s1, a2, s4h, s4l);
    // two linears; linear1 chains split output into linear2
    gemm_nt_mfma_k<<<dim3(2,128), dim3(512), 0, stream>>>(nullptr, s4h, s4l, HD,
                                                          wl1h, wl1l, b1,
                                                          nullptr, HD, l1h, l1l,
                                                          HD, 1);
    gemm_nt_mfma_k<<<dim3(2,128), dim3(512), 0, stream>>>(nullptr, l1h, l1l, HD,
                                                          wl2h, wl2l, b2,
                                                          hidden + (l+1)*HD, 768,
                                                          nullptr, nullptr, HD, 1);
  }

  // MLP head
  gemm_nt_mfma_k<<<dim3(2,128), dim3(512), 0, stream>>>(hidden, nullptr, nullptr, 768,
                                                        m1h, m1l, m1b,
                                                        nullptr, HD, m1sh, m1sl,
                                                        768, 1);
  gemm_nt_mfma_k<<<dim3(8,128), dim3(512), 0, stream>>>(nullptr, m1sh, m1sl, HD,
                                                        m2h, m2l, m2b,
                                                        Z0, OUTD, nullptr, nullptr,
                                                        HD, 2);

  // ---- linear-domain Sinkhorn ----
  rowmax_k<<<gEw, blk, 0, stream>>>(Z0, alpha);
  colmax_k<<<dim3(32,16), blk, 0, stream>>>(Z0, alpha, pmaxb);
  colred_k<<<dim3(4,16), blk, 0, stream>>>(pmaxb, beta);
  build_e_k<<<dim3(16,16,16), blk, 0, stream>>>(Z0, alpha, beta, E, Et);

  mv_k<<<gEw, blk, 0, stream>>>(E,  nullptr, av, 1);   // iter 1: b=1
  mv_k<<<gEw, blk, 0, stream>>>(Et, av,      bv, 1);
  for (int t=1; t<20; t++){
    mv_k<<<gEw, blk, 0, stream>>>(E,  bv, av, 1);
    mv_k<<<gEw, blk, 0, stream>>>(Et, av, bv, 1);
  }
  mv_k<<<gEw, blk, 0, stream>>>(E,  bv, av, 1);        // a' (row normalize)
  mv_k<<<gEw, blk, 0, stream>>>(Et, av, tv, 0);        // t' = col sums
  writep_lin_k<<<dim3(16384), blk, 0, stream>>>(E, av, tv, Pout);
}

// Round 3
// 1202.444 us; speedup vs baseline: 1.2543x; 1.0050x over previous
//
#include <hip/hip_runtime.h>
#include <cstdint>
#include <cstddef>

// Problem constants
#define BB 16
#define NN 1024
#define HD 256
#define IND 128
#define OUTD 1024
#define MROWS (BB*NN)          // 16384

#define LEAKY(x) ((x) >= 0.0f ? (x) : 0.01f*(x))

typedef short short8 __attribute__((ext_vector_type(8)));
typedef float f32x4 __attribute__((ext_vector_type(4)));

// 16B async global->LDS DMA. LDS dest is wave-uniform base + lane*16 (linear);
// swizzle is applied on the GLOBAL source address + on the ds_read side.
#define GLL16(gsrc, ldst) __builtin_amdgcn_global_load_lds( \
    (const __attribute__((address_space(1))) unsigned int*)(gsrc), \
    (__attribute__((address_space(3))) unsigned int*)(ldst), 16, 0, 0)

// compiler-level memory fence (no instruction) — prevents hoisting LDS reads
// above a raw s_barrier
#define CFENCE() asm volatile("" ::: "memory")

// ---------------- wave helpers ----------------
__device__ inline float wave_sum(float v){
  #pragma unroll
  for (int off=32; off; off>>=1) v += __shfl_xor(v, off, 64);
  return v;
}
__device__ inline float wave_max(float v){
  #pragma unroll
  for (int off=32; off; off>>=1) v = fmaxf(v, __shfl_xor(v, off, 64));
  return v;
}

// fp32 -> bf16 round-to-nearest-even; bf16 -> fp32
__device__ inline unsigned short f2bf(float x){
  unsigned u = __float_as_uint(x);
  unsigned r = (u + 0x7fffu + ((u >> 16) & 1u)) >> 16;
  return (unsigned short)r;
}
__device__ inline float bf2f(unsigned short h){
  return __uint_as_float((unsigned)h << 16);
}

// ---------------- JAX threefry2x32 gumbel noise (partitionable) ----------------
__device__ inline float gumbel_noise(unsigned m){
  const unsigned k0 = 0u, k1 = 42u;
  const unsigned ks2 = k0 ^ k1 ^ 0x1BD11BDAu;
  unsigned x0 = 0u, x1 = m;
  x0 += k0; x1 += k1;
  #define TF_ROUND(r) { x0 += x1; x1 = (x1 << (r)) | (x1 >> (32-(r))); x1 ^= x0; }
  TF_ROUND(13) TF_ROUND(15) TF_ROUND(26) TF_ROUND(6)
  x0 += k1;  x1 += ks2 + 1u;
  TF_ROUND(17) TF_ROUND(29) TF_ROUND(16) TF_ROUND(24)
  x0 += ks2; x1 += k0 + 2u;
  TF_ROUND(13) TF_ROUND(15) TF_ROUND(26) TF_ROUND(6)
  x0 += k0;  x1 += k1 + 3u;
  TF_ROUND(17) TF_ROUND(29) TF_ROUND(16) TF_ROUND(24)
  x0 += k1;  x1 += ks2 + 4u;
  TF_ROUND(13) TF_ROUND(15) TF_ROUND(26) TF_ROUND(6)
  x0 += ks2; x1 += k0 + 5u;
  #undef TF_ROUND
  unsigned bits = x0 ^ x1;
  float u = __uint_as_float((bits >> 9) | 0x3f800000u) - 1.0f;   // [0,1)
  float t = -__logf(u + 1e-20f);
  return -__logf(t + 1e-20f) * 0.05f;   // NOISE_SCALE
}

// ---------------- fused adj row stats + bf16 convert ----------------
__global__ __launch_bounds__(256) void adj_prep_k(const float* __restrict__ adj,
                                                  float* __restrict__ dis,
                                                  float* __restrict__ rinv,
                                                  unsigned short* __restrict__ abf){
  int tid = threadIdx.x, wid = tid >> 6, lane = tid & 63;
  int row = blockIdx.x*4 + wid;
  const float4* rp = (const float4*)(adj + (size_t)row*NN);
  ushort4* op = (ushort4*)(abf + (size_t)row*NN);
  float s = 0.f;
  #pragma unroll
  for (int p=0;p<4;p++){
    float4 v = rp[lane + p*64];
    s += v.x+v.y+v.z+v.w;
    ushort4 o;
    o.x = f2bf(v.x); o.y = f2bf(v.y); o.z = f2bf(v.z); o.w = f2bf(v.w);
    op[lane + p*64] = o;
  }
  s = wave_sum(s);
  if (lane==0){
    dis[row]  = 1.0f/sqrtf(s + 1.0f);
    rinv[row] = 1.0f/s;
  }
}

// ---------------- flat hi/lo split (weights, X, hidden) ----------------
__global__ __launch_bounds__(256) void split_flat_k(const float* __restrict__ src,
                                                    unsigned short* __restrict__ h,
                                                    unsigned short* __restrict__ l,
                                                    int n4){
  int gid = blockIdx.x*256 + threadIdx.x;
  if (gid >= n4) return;
  float4 v = ((const float4*)src)[gid];
  ushort4 hh, ll;
  hh.x = f2bf(v.x); ll.x = f2bf(v.x - bf2f(hh.x));
  hh.y = f2bf(v.y); ll.y = f2bf(v.y - bf2f(hh.y));
  hh.z = f2bf(v.z); ll.z = f2bf(v.z - bf2f(hh.z));
  hh.w = f2bf(v.w); ll.w = f2bf(v.w - bf2f(hh.w));
  ((ushort4*)h)[gid] = hh;
  ((ushort4*)l)[gid] = ll;
}

// fp32 [16][1024 i][ld] (cols 0..255) -> bf16 transposed [16][256 c][1024 i]
__global__ __launch_bounds__(256) void bconv_t_k(const float* __restrict__ in, int ld,
                                                 const float* __restrict__ scale,
                                                 unsigned short* __restrict__ outT){
  __shared__ float tile[64][68];
  int b  = blockIdx.z;
  int i0 = blockIdx.x*64;
  int c0 = blockIdx.y*64;
  const float* inb = in + (size_t)b*NN*ld;
  unsigned short* ob = outT + (size_t)b*HD*NN;
  int tid = threadIdx.x;
  #pragma unroll
  for (int it=0; it<4; it++){
    int f = tid + it*256;
    int r = f >> 4, c4 = (f & 15)*4;
    float4 v = *(const float4*)(inb + (size_t)(i0+r)*ld + c0 + c4);
    float s = scale ? scale[b*NN + i0 + r] : 1.0f;
    tile[r][c4+0]=v.x*s; tile[r][c4+1]=v.y*s; tile[r][c4+2]=v.z*s; tile[r][c4+3]=v.w*s;
  }
  __syncthreads();
  #pragma unroll
  for (int it=0; it<4; it++){
    int f = tid + it*256;
    int cl = f >> 4, r4 = (f & 15)*4;
    ushort4 o;
    o.x = f2bf(tile[r4+0][cl]);
    o.y = f2bf(tile[r4+1][cl]);
    o.z = f2bf(tile[r4+2][cl]);
    o.w = f2bf(tile[r4+3][cl]);
    *(ushort4*)(ob + (size_t)(c0+cl)*NN + i0 + r4) = o;
  }
}

// ---------------- MFMA batched GEMM: acc = adj[b] @ B[b] ----------------
// 4-buffer ring, stage-ahead-2, counted vmcnt, 1 barrier per K-step.
// mode 1: o = 0.5*(Bsrc[i][n] + sc_i*acc)
// mode 2: o = leaky(sc_i*(acc + sc_i*Bsrc[i][n]))
// out  (optional): o ; out2 (optional): |(sub?sub:Bsrc) - o|
__global__ __launch_bounds__(512) void gemm_nn_mfma_k(const unsigned short* __restrict__ Abf,
                                                      const unsigned short* __restrict__ Btb,
                                                      const float* __restrict__ Bsrc, int ldb,
                                                      const float* __restrict__ rowscale,
                                                      float* __restrict__ out,
                                                      float* __restrict__ out2,
                                                      const float* __restrict__ sub,
                                                      int mode){
  __shared__ unsigned short Als[4][128][32];   // 32 KB
  __shared__ unsigned short Bls[4][128][32];   // 32 KB
  int b  = blockIdx.z;
  int n0 = blockIdx.x*128;
  int i0 = blockIdx.y*128;
  const unsigned short* Ab = Abf + (size_t)b*NN*NN + (size_t)i0*NN;
  const unsigned short* Bb = Btb + (size_t)b*HD*NN + (size_t)n0*NN;
  int tid = threadIdx.x;
  int wave = tid >> 6, lane = tid & 63;
  int quad = lane >> 4, l16 = lane & 15;
  int wr = (wave >> 2)*64;
  int wc = (wave & 3)*32;

  int r  = tid >> 2;
  int cg = (((tid & 3) ^ ((r >> 1) & 3)) << 3);   // swizzled source col
  int wbase = (tid >> 6) << 9;                    // wave's 1KB chunk in a tile
  const unsigned short* gA = Ab + (size_t)r*NN + cg;
  const unsigned short* gB = Bb + (size_t)r*NN + cg;

  auto STAGE = [&](int tt){
    int buf = tt & 3;
    GLL16(gA + tt*32, &Als[buf][0][0] + wbase);
    GLL16(gB + tt*32, &Bls[buf][0][0] + wbase);
  };

  const int NT = NN/32;   // 32
  STAGE(0); STAGE(1);

  f32x4 acc[4][2] = {};

  for (int t = 0; t < NT; ++t){
    if (t+2 < NT){
      STAGE(t+2);
      asm volatile("s_waitcnt vmcnt(4)" ::: "memory");
    } else if (t+1 < NT){
      asm volatile("s_waitcnt vmcnt(2)" ::: "memory");
    } else {
      asm volatile("s_waitcnt vmcnt(0)" ::: "memory");
    }
    __builtin_amdgcn_s_barrier();
    CFENCE();
    int buf = t & 3;
    short8 af[4];
    #pragma unroll
    for (int rt=0; rt<4; rt++){
      int R = wr + rt*16 + l16;
      af[rt] = *(const short8*)&Als[buf][R][(quad ^ ((R >> 1) & 3)) << 3];
    }
    __builtin_amdgcn_s_setprio(1);
    #pragma unroll
    for (int ct=0; ct<2; ct++){
      int Rb = wc + ct*16 + l16;
      short8 bfr = *(const short8*)&Bls[buf][Rb][(quad ^ ((Rb >> 1) & 3)) << 3];
      #pragma unroll
      for (int rt=0; rt<4; rt++)
        acc[rt][ct] = __builtin_amdgcn_mfma_f32_16x16x32_bf16(af[rt], bfr, acc[rt][ct], 0, 0, 0);
    }
    __builtin_amdgcn_s_setprio(0);
  }

  #pragma unroll
  for (int rt=0; rt<4; rt++){
    #pragma unroll
    for (int p=0; p<4; p++){
      int gr = i0 + wr + rt*16 + quad*4 + p;
      int gm = b*NN + gr;
      float sc = rowscale[gm];
      #pragma unroll
      for (int ct=0; ct<2; ct++){
        int gc = n0 + wc + ct*16 + l16;
        float a = acc[rt][ct][p];
        float src = Bsrc[(size_t)gm*ldb + gc];
        float o = (mode == 1) ? 0.5f*(src + sc*a) : LEAKY(sc*(a + sc*src));
        if (out) out[(size_t)gm*HD + gc] = o;
        if (out2){
          float sv = sub ? sub[(size_t)gm*HD + gc] : src;
          out2[(size_t)gm*HD + gc] = fabsf(sv - o);
        }
      }
    }
  }
}

// ---------------- split-bf16 MFMA linear: out = act(A @ W^T + bias) ----------------
// A pre-split (Ah_/Al_), W pre-split. 3-phase K sweep: (Ah,Wh),(Al,Wh),(Ah,Wl)
// as consecutive tile ranges — same terms as interleaved 3-MFMA, 2 LDS tiles
// per stage. Same 4-buffer ring pipeline as gemm_nn.
// act 0: none, 1: leaky, 2: sinkhorn init (Z0 = (40*tanh(x)+gumbel)/0.1)
__global__ __launch_bounds__(512) void gemm_nt_mfma_k(const unsigned short* __restrict__ Ah_,
                                                      const unsigned short* __restrict__ Al_,
                                                      int lda,
                                                      const unsigned short* __restrict__ Wh_,
                                                      const unsigned short* __restrict__ Wl_,
                                                      const float* __restrict__ bias,
                                                      float* __restrict__ out, int ldo,
                                                      unsigned short* __restrict__ outh,
                                                      unsigned short* __restrict__ outl,
                                                      int K, int act){
  __shared__ unsigned short Alds[4][128][32];  // 32 KB
  __shared__ unsigned short Wlds[4][128][32];  // 32 KB
  int o0 = blockIdx.x*128, m0 = blockIdx.y*128;
  int tid = threadIdx.x;
  int wave = tid >> 6, lane = tid & 63;
  int quad = lane >> 4, l16 = lane & 15;
  int wr = (wave >> 2)*64;
  int wc = (wave & 3)*32;

  int r  = tid >> 2;
  int cg = (((tid & 3) ^ ((r >> 1) & 3)) << 3);
  int wbase = (tid >> 6) << 9;
  const unsigned short* gAh = Ah_ + (size_t)(m0 + r)*lda + cg;
  const unsigned short* gAl = Al_ + (size_t)(m0 + r)*lda + cg;
  const unsigned short* gWh = Wh_ + (size_t)(o0 + r)*K + cg;
  const unsigned short* gWl = Wl_ + (size_t)(o0 + r)*K + cg;

  int nk = K >> 5;
  int NT = 3*nk;

  auto STAGE = [&](int tt){
    int buf = tt & 3;
    const unsigned short* sa; const unsigned short* sw; int kc;
    if (tt < nk)        { sa = gAh; sw = gWh; kc = tt << 5; }
    else if (tt < 2*nk) { sa = gAl; sw = gWh; kc = (tt - nk) << 5; }
    else                { sa = gAh; sw = gWl; kc = (tt - 2*nk) << 5; }
    GLL16(sa + kc, &Alds[buf][0][0] + wbase);
    GLL16(sw + kc, &Wlds[buf][0][0] + wbase);
  };

  STAGE(0); STAGE(1);

  f32x4 acc[4][2] = {};

  for (int t = 0; t < NT; ++t){
    if (t+2 < NT){
      STAGE(t+2);
      asm volatile("s_waitcnt vmcnt(4)" ::: "memory");
    } else if (t+1 < NT){
      asm volatile("s_waitcnt vmcnt(2)" ::: "memory");
    } else {
      asm volatile("s_waitcnt vmcnt(0)" ::: "memory");
    }
    __builtin_amdgcn_s_barrier();
    CFENCE();
    int buf = t & 3;
    short8 af[4];
    #pragma unroll
    for (int rt=0; rt<4; rt++){
      int R = wr + rt*16 + l16;
      af[rt] = *(const short8*)&Alds[buf][R][(quad ^ ((R >> 1) & 3)) << 3];
    }
    __builtin_amdgcn_s_setprio(1);
    #pragma unroll
    for (int ct=0; ct<2; ct++){
      int Rb = wc + ct*16 + l16;
      short8 bfr = *(const short8*)&Wlds[buf][Rb][(quad ^ ((Rb >> 1) & 3)) << 3];
      #pragma unroll
      for (int rt=0; rt<4; rt++)
        acc[rt][ct] = __builtin_amdgcn_mfma_f32_16x16x32_bf16(af[rt], bfr, acc[rt][ct], 0, 0, 0);
    }
    __builtin_amdgcn_s_setprio(0);
  }

  #pragma unroll
  for (int rt=0; rt<4; rt++){
    #pragma unroll
    for (int p=0; p<4; p++){
      int gm = m0 + wr + rt*16 + quad*4 + p;
      #pragma unroll
      for (int ct=0; ct<2; ct++){
        int gc = o0 + wc + ct*16 + l16;
        float v = acc[rt][ct][p] + bias[gc];
        if (act == 1){
          v = LEAKY(v);
        } else if (act == 2){
          // fast tanh: clamp then (e^{2x}-1)/(e^{2x}+1); tanh(15)==1 in fp32
          float vcl = fminf(fmaxf(v, -15.f), 15.f);
          float e = __expf(2.f*vcl);
          float lg = 40.0f * (e - 1.f) / (e + 1.f);
          unsigned flat = (unsigned)gm*1024u + (unsigned)gc;
          v = (lg + gumbel_noise(flat)) / 0.1f;
        }
        if (out) out[(size_t)gm*ldo + gc] = v;
        if (outh){
          unsigned short hh = f2bf(v);
          outh[(size_t)gm*ldo + gc] = hh;
          outl[(size_t)gm*ldo + gc] = f2bf(v - bf2f(hh));
        }
      }
    }
  }
}

// ---------------- channel attention + combine (writes split bf16 hi/lo) ----------------
__global__ __launch_bounds__(256) void attn_k(const float* __restrict__ c0,
                                              const float* __restrict__ s0,
                                              const float* __restrict__ s1,
                                              const float* __restrict__ s2,
                                              const float* __restrict__ a2,
                                              unsigned short* __restrict__ outh,
                                              unsigned short* __restrict__ outl){
  int tid = threadIdx.x, wid = tid >> 6, lane = tid & 63;
  int row = blockIdx.x*4 + wid;
  size_t base = (size_t)row*HD + lane*4;
  float4 av = *(const float4*)(a2 + lane*4);
  float4 v[4];
  v[0] = *(const float4*)(c0 + base);
  v[1] = *(const float4*)(s0 + base);
  v[2] = *(const float4*)(s1 + base);
  v[3] = *(const float4*)(s2 + base);
  float e[4];
  #pragma unroll
  for (int c=0;c<4;c++){
    float p = fmaxf(v[c].x,0.f)*av.x + fmaxf(v[c].y,0.f)*av.y
            + fmaxf(v[c].z,0.f)*av.z + fmaxf(v[c].w,0.f)*av.w;
    e[c] = wave_sum(p);
  }
  float m = fmaxf(fmaxf(e[0],e[1]), fmaxf(e[2],e[3]));
  float w0 = expf(e[0]-m), w1 = expf(e[1]-m), w2 = expf(e[2]-m), w3 = expf(e[3]-m);
  float inv = 0.25f / (w0+w1+w2+w3);
  float4 o;
  o.x = (w0*v[0].x + w1*v[1].x + w2*v[2].x + w3*v[3].x)*inv;
  o.y = (w0*v[0].y + w1*v[1].y + w2*v[2].y + w3*v[3].y)*inv;
  o.z = (w0*v[0].z + w1*v[1].z + w2*v[2].z + w3*v[3].z)*inv;
  o.w = (w0*v[0].w + w1*v[1].w + w2*v[2].w + w3*v[3].w)*inv;
  ushort4 oh, ol;
  oh.x = f2bf(o.x); ol.x = f2bf(o.x - bf2f(oh.x));
  oh.y = f2bf(o.y); ol.y = f2bf(o.y - bf2f(oh.y));
  oh.z = f2bf(o.z); ol.z = f2bf(o.z - bf2f(oh.z));
  oh.w = f2bf(o.w); ol.w = f2bf(o.w - bf2f(oh.w));
  *(ushort4*)(outh + base) = oh;
  *(ushort4*)(outl + base) = ol;
}

// ================= linear-domain Sinkhorn =================
__global__ __launch_bounds__(256) void rowmax_k(const float* __restrict__ Z,
                                                float* __restrict__ alpha){
  int tid = threadIdx.x, wid = tid >> 6, lane = tid & 63;
  int row = blockIdx.x*4 + wid;
  const float4* rp = (const float4*)(Z + (size_t)row*NN);
  float m = -3.4e38f;
  #pragma unroll
  for (int p=0;p<4;p++){
    float4 v = rp[lane + p*64];
    m = fmaxf(m, fmaxf(fmaxf(v.x,v.y), fmaxf(v.z,v.w)));
  }
  m = wave_max(m);
  if (lane==0) alpha[row] = m;
}

__global__ __launch_bounds__(256) void colmax_k(const float* __restrict__ Z,
                                                const float* __restrict__ alpha,
                                                float* __restrict__ pmax){
  int b = blockIdx.y, rc = blockIdx.x;
  int j = threadIdx.x*4;
  const float* Zb = Z + (size_t)b*NN*NN;
  const float* ab = alpha + b*NN;
  float4 m = make_float4(-3.4e38f,-3.4e38f,-3.4e38f,-3.4e38f);
  int r0 = rc*32;
  #pragma unroll 4
  for (int r=r0; r<r0+32; r++){
    float4 v = *(const float4*)(Zb + (size_t)r*NN + j);
    float a = ab[r];
    m.x = fmaxf(m.x, v.x-a); m.y = fmaxf(m.y, v.y-a);
    m.z = fmaxf(m.z, v.z-a); m.w = fmaxf(m.w, v.w-a);
  }
  *(float4*)(pmax + ((size_t)b*32 + rc)*NN + j) = m;
}

__global__ __launch_bounds__(256) void colred_k(const float* __restrict__ pmax,
                                                float* __restrict__ beta){
  int b = blockIdx.y;
  int j = blockIdx.x*256 + threadIdx.x;
  float m = -3.4e38f;
  #pragma unroll
  for (int rc=0; rc<32; rc++)
    m = fmaxf(m, pmax[((size_t)b*32+rc)*NN + j]);
  beta[b*NN + j] = m;
}

__global__ __launch_bounds__(256) void build_e_k(const float* __restrict__ Z,
                                                 const float* __restrict__ alpha,
                                                 const float* __restrict__ beta,
                                                 unsigned short* __restrict__ E,
                                                 unsigned short* __restrict__ Et){
  __shared__ float tile[64][65];
  int b = blockIdx.z;
  int i0 = blockIdx.y*64, j0 = blockIdx.x*64;
  const float* Zb = Z + (size_t)b*NN*NN;
  const float* ab = alpha + b*NN;
  const float* bb = beta  + b*NN;
  unsigned short* Eb  = E  + (size_t)b*NN*NN;
  unsigned short* Etb = Et + (size_t)b*NN*NN;
  int tid = threadIdx.x;
  #pragma unroll
  for (int it=0; it<4; it++){
    int f = tid + it*256;
    int r = f >> 4, c4 = (f & 15)*4;
    float4 v = *(const float4*)(Zb + (size_t)(i0+r)*NN + j0 + c4);
    float a = ab[i0+r];
    float e0 = __expf(v.x - a - bb[j0+c4+0]);
    float e1 = __expf(v.y - a - bb[j0+c4+1]);
    float e2 = __expf(v.z - a - bb[j0+c4+2]);
    float e3 = __expf(v.w - a - bb[j0+c4+3]);
    tile[r][c4+0]=e0; tile[r][c4+1]=e1; tile[r][c4+2]=e2; tile[r][c4+3]=e3;
    ushort4 o; o.x=f2bf(e0); o.y=f2bf(e1); o.z=f2bf(e2); o.w=f2bf(e3);
    *(ushort4*)(Eb + (size_t)(i0+r)*NN + j0 + c4) = o;
  }
  __syncthreads();
  #pragma unroll
  for (int it=0; it<4; it++){
    int f = tid + it*256;
    int r = f >> 4, c4 = (f & 15)*4;
    ushort4 o;
    o.x = f2bf(tile[c4+0][r]);
    o.y = f2bf(tile[c4+1][r]);
    o.z = f2bf(tile[c4+2][r]);
    o.w = f2bf(tile[c4+3][r]);
    *(ushort4*)(Etb + (size_t)(j0+r)*NN + i0 + c4) = o;
  }
}

// w[row] = (recip ? 1/ : ) sum_j M[row][j] * v[b][j]; v==null -> v=1
__global__ __launch_bounds__(256) void mv_k(const unsigned short* __restrict__ M,
                                            const float* __restrict__ v,
                                            float* __restrict__ w, int recip){
  int tid = threadIdx.x, wid = tid >> 6, lane = tid & 63;
  int row = blockIdx.x*4 + wid;
  int b = row >> 10;
  const unsigned short* mp = M + (size_t)row*NN + lane*16;
  float s = 0.f;
  if (v){
    const float* vb = v + b*NN + lane*16;
    #pragma unroll
    for (int h2=0; h2<2; h2++){
      short8 m8 = *(const short8*)(mp + h2*8);
      float4 v0 = *(const float4*)(vb + h2*8);
      float4 v1 = *(const float4*)(vb + h2*8 + 4);
      s += bf2f((unsigned short)m8[0])*v0.x + bf2f((unsigned short)m8[1])*v0.y
         + bf2f((unsigned short)m8[2])*v0.z + bf2f((unsigned short)m8[3])*v0.w
         + bf2f((unsigned short)m8[4])*v1.x + bf2f((unsigned short)m8[5])*v1.y
         + bf2f((unsigned short)m8[6])*v1.z + bf2f((unsigned short)m8[7])*v1.w;
    }
  } else {
    #pragma unroll
    for (int h2=0; h2<2; h2++){
      short8 m8 = *(const short8*)(mp + h2*8);
      #pragma unroll
      for (int q=0;q<8;q++) s += bf2f((unsigned short)m8[q]);
    }
  }
  s = wave_sum(s);
  if (lane==0) w[row] = recip ? 1.0f/s : s;
}

// P_ij = E_ij * a'_i / t'_j
__global__ __launch_bounds__(256) void writep_lin_k(const unsigned short* __restrict__ E,
                                                    const float* __restrict__ ap,
                                                    const float* __restrict__ tp,
                                                    float* __restrict__ P){
  int gid = blockIdx.x*256 + threadIdx.x;
  int row = gid >> 8;
  int j = (gid & 255)*4;
  int b = row >> 10;
  ushort4 e = ((const ushort4*)E)[gid];
  float a = ap[row];
  float4 t = *(const float4*)(tp + (size_t)b*NN + j);
  float4 o;
  o.x = bf2f(e.x)*a/t.x;
  o.y = bf2f(e.y)*a/t.y;
  o.z = bf2f(e.z)*a/t.z;
  o.w = bf2f(e.w)*a/t.w;
  ((float4*)P)[gid] = o;
}

// ---------------- host orchestration ----------------
extern "C" void kernel_launch(void* const* d_in, const int* in_sizes, int n_in,
                              void* d_out, int out_size, void* d_ws, size_t ws_size,
                              hipStream_t stream){
  const float* X    = (const float*)d_in[0];
  const float* adj  = (const float*)d_in[1];
  const float* w_in = (const float*)d_in[2];
  const float* b_in = (const float*)d_in[3];
  const float* cw1  = (const float*)d_in[4];
  const float* cb1  = (const float*)d_in[5];
  const float* cw2  = (const float*)d_in[6];
  const float* cb2  = (const float*)d_in[7];
  const float* ca   = (const float*)d_in[8];
  const float* m1w  = (const float*)d_in[9];
  const float* m1b  = (const float*)d_in[10];
  const float* m2w  = (const float*)d_in[11];
  const float* m2b  = (const float*)d_in[12];

  float* outp = (float*)d_out;
  float* Pout = outp;                              // [0,16M) floats
  float* Z0   = outp + (size_t)16*1024*1024;       // [16M,32M) = bytes [64,128)MB

  const size_t SLOT = (size_t)4*1024*1024;
  float* s1 = outp + 0*SLOT;
  float* s2 = outp + 1*SLOT;
  float* s3 = outp + 2*SLOT;
  float* s4 = outp + 3*SLOT;
  float* s5 = outp + 4*SLOT;
  unsigned short* adjbf = (unsigned short*)(outp + 6*SLOT);   // [96,128) MB

  unsigned short* Xh  = (unsigned short*)(outp + 0*SLOT);
  unsigned short* Xl  = Xh + (size_t)MROWS*IND;
  unsigned short* s4h = (unsigned short*)(outp + 3*SLOT);
  unsigned short* s4l = s4h + (size_t)MROWS*HD;
  unsigned short* l1h = (unsigned short*)(outp + 0*SLOT);
  unsigned short* l1l = l1h + (size_t)MROWS*HD;
  unsigned short* m1sh = (unsigned short*)(outp + 1*SLOT);
  unsigned short* m1sl = m1sh + (size_t)MROWS*HD;
  // hidden split for mlp1: slots 2-4 ([32,80) MB; overlaps Z0's low half but
  // dead before mlp2 writes Z0)
  unsigned short* Hh = (unsigned short*)(outp + 2*SLOT);      // 24 MB
  unsigned short* Hl = Hh + (size_t)MROWS*768;                // 24 MB
  // sinkhorn stabilizers in slot 0 (dead before P write)
  float* alpha = s1;                 // 64 KB
  float* beta  = s1 + 16384;         // 64 KB
  float* pmaxb = s1 + 32768;         // 2 MB

  float* ws     = (float*)d_ws;
  float* hidden = ws;                                   // 12M floats (layers)
  float* dis    = ws + (size_t)12*1024*1024;
  float* rinv   = dis + 16384;
  unsigned short* bt = (unsigned short*)(rinv + 16384); // 8 MiB
  unsigned short* wsp = (unsigned short*)(ws + (size_t)15*1024*1024);
  unsigned short* winh = wsp;               unsigned short* winl = winh + 32768;
  unsigned short* w1h  = winl + 32768;      unsigned short* w1l  = w1h + 131072;
  unsigned short* w2h  = w1l + 131072;      unsigned short* w2l  = w2h + 131072;
  unsigned short* m1h  = w2l + 131072;      unsigned short* m1l  = m1h + 196608;
  unsigned short* m2h  = m1l + 196608;      unsigned short* m2l  = m2h + 262144;
  unsigned short* E  = (unsigned short*)ws;             // 32 MiB (post-layers)
  unsigned short* Et = E + (size_t)MROWS*NN;            // 32 MiB
  float* av = ws + (size_t)16*1024*1024;
  float* bv = av + 16384;
  float* tv = bv + 16384;

  dim3 blk(256);
  dim3 gEw(4096);
  dim3 gMM(2, 8, 16);
  dim3 gCT(16, 4, 16);

  adj_prep_k<<<gEw, blk, 0, stream>>>(adj, dis, rinv, adjbf);
  split_flat_k<<<dim3(32),  blk, 0, stream>>>(w_in, winh, winl, 8192);
  split_flat_k<<<dim3(128), blk, 0, stream>>>(cw1,  w1h,  w1l,  32768);
  split_flat_k<<<dim3(128), blk, 0, stream>>>(cw2,  w2h,  w2l,  32768);
  split_flat_k<<<dim3(192), blk, 0, stream>>>(m1w,  m1h,  m1l,  49152);
  split_flat_k<<<dim3(256), blk, 0, stream>>>(m2w,  m2h,  m2l,  65536);
  split_flat_k<<<dim3(2048), blk, 0, stream>>>(X, Xh, Xl, 524288);

  // input projection: hidden[:, 0:256] = X @ w_in^T + b_in
  gemm_nt_mfma_k<<<dim3(2,128), dim3(512), 0, stream>>>(Xh, Xl, IND,
                                                        winh, winl, b_in,
                                                        hidden, 768, nullptr, nullptr,
                                                        IND, 0);

  for (int l=0; l<2; l++){
    const float* h_in = hidden + l*HD;       // ld 768
    unsigned short* wl1h = w1h + (size_t)l*65536;
    unsigned short* wl1l = w1l + (size_t)l*65536;
    unsigned short* wl2h = w2h + (size_t)l*65536;
    unsigned short* wl2l = w2l + (size_t)l*65536;
    const float* b1 = cb1 + (size_t)l*HD;
    const float* b2 = cb2 + (size_t)l*HD;
    const float* a2 = ca  + (size_t)l*2*HD + HD;

    // C0 = leaky(A_hat h)
    bconv_t_k<<<gCT, blk, 0, stream>>>(h_in, 768, dis, bt);
    gemm_nn_mfma_k<<<gMM, dim3(512), 0, stream>>>(adjbf, bt, h_in, 768, dis, s2, nullptr, nullptr, 2);
    // t1 = P h ; S0 = |h - t1| (fused)
    bconv_t_k<<<gCT, blk, 0, stream>>>(h_in, 768, nullptr, bt);
    gemm_nn_mfma_k<<<gMM, dim3(512), 0, stream>>>(adjbf, bt, h_in, 768, rinv, s1, s3, nullptr, 1);
    // t2 = P t1 ; S1 = |t1 - t2| (fused)
    bconv_t_k<<<gCT, blk, 0, stream>>>(s1, HD, nullptr, bt);
    gemm_nn_mfma_k<<<gMM, dim3(512), 0, stream>>>(adjbf, bt, s1, HD, rinv, s4, s5, nullptr, 1);
    // t3 = P t2
    bconv_t_k<<<gCT, blk, 0, stream>>>(s4, HD, nullptr, bt);
    gemm_nn_mfma_k<<<gMM, dim3(512), 0, stream>>>(adjbf, bt, s4, HD, rinv, s1, nullptr, nullptr, 1);
    // t4 = P t3 ; S2 = |t2 - t4| (fused, t4 discarded)
    bconv_t_k<<<gCT, blk, 0, stream>>>(s1, HD, nullptr, bt);
    gemm_nn_mfma_k<<<gMM, dim3(512), 0, stream>>>(adjbf, bt, s1, HD, rinv, nullptr, s1, s4, 1);
    // attention combine -> split bf16 (slot3: t2 dead)
    attn_k<<<gEw, blk, 0, stream>>>(s2, s3, s5, s1, a2, s4h, s4l);
    // two linears; linear1 chains split output into linear2
    gemm_nt_mfma_k<<<dim3(2,128), dim3(512), 0, stream>>>(s4h, s4l, HD,
                                                          wl1h, wl1l, b1,
                                                          nullptr, HD, l1h, l1l,
                                                          HD, 1);
    gemm_nt_mfma_k<<<dim3(2,128), dim3(512), 0, stream>>>(l1h, l1l, HD,
                                                          wl2h, wl2l, b2,
                                                          hidden + (l+1)*HD, 768,
                                                          nullptr, nullptr, HD, 1);
  }

  // MLP head: split hidden once, then two pre-split GEMMs
  split_flat_k<<<dim3(12288), blk, 0, stream>>>(hidden, Hh, Hl, 3145728);
  gemm_nt_mfma_k<<<dim3(2,128), dim3(512), 0, stream>>>(Hh, Hl, 768,
                                                        m1h, m1l, m1b,
                                                        nullptr, HD, m1sh, m1sl,
                                                        768, 1);
  gemm_nt_mfma_k<<<dim3(8,128), dim3(512), 0, stream>>>(m1sh, m1sl, HD,
                                                        m2h, m2l, m2b,
                                                        Z0, OUTD, nullptr, nullptr,
                                                        HD, 2);

  // ---- linear-domain Sinkhorn ----
  rowmax_k<<<gEw, blk, 0, stream>>>(Z0, alpha);
  colmax_k<<<dim3(32,16), blk, 0, stream>>>(Z0, alpha, pmaxb);
  colred_k<<<dim3(4,16), blk, 0, stream>>>(pmaxb, beta);
  build_e_k<<<dim3(16,16,16), blk, 0, stream>>>(Z0, alpha, beta, E, Et);

  mv_k<<<gEw, blk, 0, stream>>>(E,  nullptr, av, 1);   // iter 1: b=1
  mv_k<<<gEw, blk, 0, stream>>>(Et, av,      bv, 1);
  for (int t=1; t<20; t++){
    mv_k<<<gEw, blk, 0, stream>>>(E,  bv, av, 1);
    mv_k<<<gEw, blk, 0, stream>>>(Et, av, bv, 1);
  }
  mv_k<<<gEw, blk, 0, stream>>>(E,  bv, av, 1);        // a' (row normalize)
  mv_k<<<gEw, blk, 0, stream>>>(Et, av, tv, 0);        // t' = col sums
  writep_lin_k<<<dim3(16384), blk, 0, stream>>>(E, av, tv, Pout);
}